// Round 6
// baseline (375956.348 us; speedup 1.0000x reference)
//
#include <hip/hip_runtime.h>
#include <math.h>

// ---------------- problem sizes ----------------
#define NN   2048   // source length
#define TLEN 2048   // target length
#define TTAG 64     // tags
#define VOC  50257
#define GW   16     // replicated decoder blocks (each owns CHK source rows)
#define CHK  128    // source rows per block
#define RECW 192    // u64 words per record slot (1.5 KB stride)
#define DIAG_T 8192 // diagnostic step count (4x real -> visible in top-5 iff >=8.5us/step)
static_assert(GW * CHK == NN, "chunking");

// ---------------- workspace layout (float units) ----------------
#define OFF_XF    0                          // NN*400   (reused as kDec<0> dummy hout after kEnc)
#define OFF_XB    (OFF_XF  + NN*400)         // NN*400   (first 16K floats reused as diag records/sink after kEnc)
#define OFF_TGX   (OFF_XB  + NN*400)         // TTAG*400
#define OFF_PEW   (OFF_TGX + TTAG*400)       // TLEN*400
#define OFF_ENC   (OFF_PEW + TLEN*400)       // NN*200
#define OFF_W1DT  (OFF_ENC + NN*200)         // NN*100
#define OFF_TAGV  (OFF_W1DT+ NN*100)         // TTAG*100
#define OFF_TGW1  (OFF_TAGV+ TTAG*100)       // TTAG*100
#define OFF_TGW   (OFF_TGW1+ TTAG*100)       // TTAG*400
#define OFF_HOUT  (OFF_TGW + TTAG*400)       // TLEN*100
#define OFF_REC   (OFF_HOUT+ TLEN*100)       // 2*GW*RECW u64
#define OFF_PB    (OFF_REC + 2*GW*RECW*2)    // loss partials

// record u64 word map: [0..99] ctxp bf16-pairs, [100..163] score bf16-pairs (128 rows),
//                      [164] m(f32), [165] S(f32), [166] amax val(f32), [167] amax idx(i32)
// each u64 = {payload u32 (lo), seq u32 (hi)}  -> single-word atomicity, no fences.

// ---------------- helpers ----------------
__device__ __forceinline__ float sigf(float x){ return 1.0f/(1.0f+__expf(-x)); }
__device__ __forceinline__ float tanhfast(float x){
  float e = __expf(2.0f*x);
  return 1.0f - 2.0f/(e+1.0f);
}
__device__ __forceinline__ unsigned short f2b(float x){
  unsigned b=__float_as_uint(x);
  return (unsigned short)((b + 0x7fffu + ((b>>16)&1u))>>16);
}
__device__ __forceinline__ unsigned pk2(float a,float b){ return (unsigned)f2b(a) | ((unsigned)f2b(b)<<16); }
__device__ __forceinline__ float blo(unsigned u){ return __uint_as_float(u<<16); }
__device__ __forceinline__ float bhi(unsigned u){ return __uint_as_float(u&0xffff0000u); }

__device__ __forceinline__ unsigned long long ald64(const unsigned long long* p){
  return __hip_atomic_load(p,__ATOMIC_RELAXED,__HIP_MEMORY_SCOPE_SYSTEM);
}
__device__ __forceinline__ void ast64(unsigned long long* p, unsigned long long v){
  __hip_atomic_store(p,v,__ATOMIC_RELAXED,__HIP_MEMORY_SCOPE_SYSTEM);
}
__device__ __forceinline__ unsigned long long mkw(unsigned pay, unsigned seq){
  return (unsigned long long)pay | ((unsigned long long)seq<<32);
}

// ---------------- kInit: zero record region (every launch / replay) ----------------
__global__ void kInit(float* ws){
  unsigned long long* r = (unsigned long long*)(ws + OFF_REC);
  int i = blockIdx.x*256 + threadIdx.x;
  if (i < 2*GW*RECW) ast64(r+i, 0ull);
}

// ---------------- kPrep: all input-side GEMVs (parallel) ----------------
__global__ __launch_bounds__(512) void kPrep(
    const int* src, const int* tag, const int* oid,
    const float* emb_char, const float* emb_tag,
    const float* fWih, const float* fb,
    const float* bWih, const float* bb,
    const float* tWih, const float* tb,
    const float* dWih, const float* db, float* ws)
{
  int r = blockIdx.x, j = threadIdx.x;
  if (j >= 400) return;
  if (r < NN) {
    const float* e = emb_char + (size_t)src[r]*32;
    const float* Wr = fWih + j*32;
    float a = fb[j];
    #pragma unroll
    for (int q=0;q<32;q++) a += e[q]*Wr[q];
    ws[OFF_XF + r*400 + j] = a;
  } else if (r < 2*NN) {
    int n = r - NN;
    const float* e = emb_char + (size_t)src[n]*32;
    const float* Wr = bWih + j*32;
    float a = bb[j];
    #pragma unroll
    for (int q=0;q<32;q++) a += e[q]*Wr[q];
    ws[OFF_XB + n*400 + j] = a;
  } else if (r < 2*NN + TTAG) {
    int s = r - 2*NN;
    const float* e = emb_tag + (size_t)tag[s]*32;
    const float* Wr = tWih + j*32;
    float a = tb[j];
    #pragma unroll
    for (int q=0;q<32;q++) a += e[q]*Wr[q];
    ws[OFF_TGX + s*400 + j] = a;
  } else {
    int t = r - (2*NN + TTAG);
    int pid = (t==0) ? 0 : oid[t-1];
    const float* e = emb_char + (size_t)pid*32;
    const float* Wr = dWih + (size_t)j*332 + 300;
    float a = db[j];
    #pragma unroll
    for (int q=0;q<32;q++) a += e[q]*Wr[q];
    ws[OFF_PEW + t*400 + j] = a;
  }
}

// ---------------- kEnc: sequential LSTM scans (3 independent blocks) ----------------
struct EncShared {
  float tvs[TTAG*100];
  float sa [TTAG*64];
  float hbuf[100];
  float zbuf[400];
};

__device__ void lstm_block(const float* Whh, const float* xbase, float* ws,
                           int reverse, int col, EncShared* sh)
{
  int tid = threadIdx.x;
  float whh[100];
  if (tid < 400){
    #pragma unroll
    for (int k=0;k<100;k++) whh[k] = Whh[tid*100+k];
  }
  float c = 0.f;
  if (tid < 100) sh->hbuf[tid] = 0.f;
  __syncthreads();
  for (int i=0;i<NN;i++){
    int n = reverse ? (NN-1-i) : i;
    if (tid < 400){
      float z = xbase[n*400+tid];
      #pragma unroll 10
      for (int k=0;k<100;k++) z += whh[k]*sh->hbuf[k];
      sh->zbuf[tid] = z;
    }
    __syncthreads();
    if (tid < 100){
      float zi=sh->zbuf[tid], zf=sh->zbuf[tid+100], zg=sh->zbuf[tid+200], zo=sh->zbuf[tid+300];
      c = sigf(zf)*c + sigf(zi)*tanhfast(zg);
      float h = sigf(zo)*tanhfast(c);
      sh->hbuf[tid] = h;
      ws[OFF_ENC + n*200 + col + tid] = h;
    }
    __syncthreads();
  }
}

__global__ __launch_bounds__(512,1) void kEnc(
    const float* fWhh, const float* bWhh, const float* tWhh,
    const float* taw1, const float* dWih, float* ws)
{
  __shared__ EncShared sh;
  int b = blockIdx.x, tid = threadIdx.x;
  if (b == 0){ lstm_block(fWhh, ws+OFF_XF, ws, 0, 0,   &sh); return; }
  if (b == 1){ lstm_block(bWhh, ws+OFF_XB, ws, 1, 100, &sh); return; }

  // ---- block 2: tag LSTM + self-attn + tagv-derived tables ----
  {
    float whh[100];
    if (tid<400){
      #pragma unroll
      for (int k=0;k<100;k++) whh[k] = tWhh[tid*100+k];
    }
    float c = 0.f;
    if (tid<100) sh.hbuf[tid] = 0.f;
    __syncthreads();
    for (int s=0;s<TTAG;s++){
      if (tid<400){
        float z = ws[OFF_TGX + s*400 + tid];
        #pragma unroll 10
        for (int k=0;k<100;k++) z += whh[k]*sh.hbuf[k];
        sh.zbuf[tid] = z;
      }
      __syncthreads();
      if (tid<100){
        float zi=sh.zbuf[tid], zf=sh.zbuf[tid+100], zg=sh.zbuf[tid+200], zo=sh.zbuf[tid+300];
        c = sigf(zf)*c + sigf(zi)*tanhfast(zg);
        float h = sigf(zo)*tanhfast(c);
        sh.hbuf[tid] = h;
        sh.tvs[s*100+tid] = h;
      }
      __syncthreads();
    }
  }
  for (int idx=tid; idx<TTAG*TTAG; idx+=512){
    int s=idx>>6, t2=idx&63;
    float a=0.f;
    #pragma unroll 10
    for (int h=0;h<100;h++) a += sh.tvs[s*100+h]*sh.tvs[t2*100+h];
    sh.sa[idx]=a;
  }
  __syncthreads();
  if (tid<TTAG){
    float m=-1e30f;
    for (int t2=0;t2<64;t2++) m = fmaxf(m, sh.sa[tid*64+t2]);
    float sum=0.f;
    for (int t2=0;t2<64;t2++){ float e=__expf(sh.sa[tid*64+t2]-m); sh.sa[tid*64+t2]=e; sum+=e; }
    float r=1.f/sum;
    for (int t2=0;t2<64;t2++) sh.sa[tid*64+t2]*=r;
  }
  __syncthreads();
  float tvloc[13]; int cnt=0;
  for (int idx=tid; idx<TTAG*100; idx+=512){
    int t2=idx/100, hh=idx%100;
    float a = sh.tvs[t2*100+hh];
    for (int s=0;s<64;s++) a += sh.tvs[s*100+hh]*sh.sa[s*64+t2];
    tvloc[cnt++]=a;
    ws[OFF_TAGV+idx]=a;
  }
  __syncthreads();
  float* tagvs = sh.sa;
  cnt=0;
  for (int idx=tid; idx<TTAG*100; idx+=512) tagvs[idx]=tvloc[cnt++];
  __syncthreads();
  for (int idx=tid; idx<TTAG*100; idx+=512){
    int s=idx/100, k=idx%100;
    float a=0.f;
    #pragma unroll 10
    for (int h=0;h<100;h++) a += tagvs[s*100+h]*taw1[k*100+h];
    ws[OFF_TGW1+idx]=a;
  }
  for (int idx=tid; idx<TTAG*400; idx+=512){
    int s=idx/400, j=idx%400;
    const float* Wr = dWih + (size_t)j*332 + 200;
    float a=0.f;
    #pragma unroll 10
    for (int h=0;h<100;h++) a += tagvs[s*100+h]*Wr[h];
    ws[OFF_TGW+idx]=a;
  }
}

// ---------------- kMid: w1dt = enc @ attn_w1.T ----------------
__global__ void kMid(const float* aw1, float* ws){
  __shared__ float er[200];
  int n=blockIdx.x, tid=threadIdx.x;
  for (int i=tid;i<200;i+=128) er[i]=ws[OFF_ENC+n*200+i];
  __syncthreads();
  if (tid<100){
    const float* Wr = aw1 + tid*200;
    float a=0.f;
    #pragma unroll 8
    for (int d=0;d<200;d++) a += er[d]*Wr[d];
    ws[OFF_W1DT + n*100 + tid]=a;
  }
}

// ---------------- kDiagComm: pure sync cost, dependency-chained, one word/block/step ----------------
// MODE 0: plain relaxed system store publish (current mechanism)
// MODE 1: atomicExch publish (forced prompt coherence-point service)
template<int MODE>
__global__ __launch_bounds__(64) void kDiagComm(float* ws, int steps, int roff){
  unsigned long long* REC = (unsigned long long*)(ws + OFF_XB + roff);
  const int w = blockIdx.x;
  const int l = threadIdx.x;
  unsigned carry = 0;
  for (int t=0; t<steps; ++t){
    const int p = t&1;
    const unsigned seq = (unsigned)(t+1);
    unsigned long long* slot = REC + (size_t)p*GW*16;
    if (l==0){
      unsigned long long v = mkw(carry, seq);
      if (MODE==0) ast64(slot + (size_t)w*16, v);
      else (void)__hip_atomic_exchange(slot + (size_t)w*16, v, __ATOMIC_RELAXED, __HIP_MEMORY_SCOPE_SYSTEM);
    }
    unsigned pay=0;
    if (l<GW){
      const unsigned long long* rp = slot + (size_t)l*16;
      unsigned long long v = ald64(rp);
      while ((unsigned)(v>>32)!=seq){ __builtin_amdgcn_s_sleep(1); v = ald64(rp); }
      pay = (unsigned)v;
    }
    for (int d=1;d<64;d<<=1) pay += __shfl_xor(pay,d,64);
    carry = pay + 1;   // chain: next publish depends on this gather
  }
  if (l==0) ((unsigned*)(ws+OFF_XB))[8192 + MODE*64 + w] = carry;  // anti-DCE sink (scratch)
}

// ---------------- kDec<COMM>: replicated decoder; COMM=0 -> local stand-ins (no sync) ----------------
template<int COMM>
__global__ __launch_bounds__(512,1) void kDec(
    const float* dWhh, const float* dWih,
    const float* aw2, const float* aw3, const float* av,
    const float* taw2, const float* tav, float* ws, int steps)
{
  __shared__ unsigned aw2L[100*100];
  __shared__ unsigned tw1L[TTAG*50];
  __shared__ unsigned tagvL[TTAG*50];
  __shared__ unsigned w1L[CHK*50];
  __shared__ unsigned encL[CHK*100];
  __shared__ unsigned ctxS[GW*100];
  __shared__ float tavL[100], avL[100], aw3L[500];
  __shared__ float hL[100], cL[100], tcL[100], tsaL[100], nsL[200];
  __shared__ float uL[TTAG], tawL[TTAG];
  __shared__ float zpreL[400], ctxL[200], a23L[100], ctxpL[200];
  __shared__ float srowL[CHK], eRL[CHK];
  __shared__ float mwL[GW], SwL[GW], avvL[GW], sclL[GW];
  __shared__ int   aiL[GW];
  __shared__ float hdrL[4];
  __shared__ float prevL[5];
  __shared__ float MS[2];
  __shared__ int   amiL;
  __shared__ float elL[200];

  const int tid = threadIdx.x;
  const int w   = blockIdx.x;
  unsigned long long* REC = (unsigned long long*)(ws + OFF_REC);
  float* hout = ws + (COMM ? OFF_HOUT : OFF_XF);   // diag writes to scratch

  unsigned wihc[100];  // dec_Wih[j,0:200]
  unsigned wiht[50];   // dec_Wih[j,200:300]  (E2: tc·wiht replaces taw@TGW)
  unsigned whhr[50];   // dec_Whh[j,:]
  unsigned tw2r[25];   // tag_attn_w2[k, q*50 : +50]
  if (tid < 400){
    #pragma unroll
    for (int i=0;i<100;i++) wihc[i] = pk2(dWih[(size_t)tid*332+2*i], dWih[(size_t)tid*332+2*i+1]);
    #pragma unroll
    for (int i=0;i<50;i++)  wiht[i] = pk2(dWih[(size_t)tid*332+200+2*i], dWih[(size_t)tid*332+200+2*i+1]);
    #pragma unroll
    for (int i=0;i<50;i++)  whhr[i] = pk2(dWhh[tid*100+2*i], dWhh[tid*100+2*i+1]);
    int k = tid>>2, off = (tid&3)*50;
    #pragma unroll
    for (int i=0;i<25;i++)  tw2r[i] = pk2(taw2[k*200+off+2*i], taw2[k*200+off+2*i+1]);
  }
  for (int i=tid;i<100*100;i+=512){ int k=i/100,d2=i%100; aw2L[i]=pk2(aw2[k*200+2*d2], aw2[k*200+2*d2+1]); }
  for (int i=tid;i<TTAG*50;i+=512){ int ss=i/50,k2=i%50; tw1L[i]=pk2(ws[OFF_TGW1+ss*100+2*k2], ws[OFF_TGW1+ss*100+2*k2+1]); }
  for (int i=tid;i<TTAG*50;i+=512){ int ss=i/50,h2=i%50; tagvL[i]=pk2(ws[OFF_TAGV+ss*100+2*h2], ws[OFF_TAGV+ss*100+2*h2+1]); }
  for (int i=tid;i<CHK*50;i+=512){ int r=i/50,k2=i%50; w1L[i]=pk2(ws[OFF_W1DT+(w*CHK+r)*100+2*k2], ws[OFF_W1DT+(w*CHK+r)*100+2*k2+1]); }
  for (int i=tid;i<CHK*100;i+=512){ int r=i/100,d2=i%100; encL[i]=pk2(ws[OFF_ENC+(w*CHK+r)*200+2*d2], ws[OFF_ENC+(w*CHK+r)*200+2*d2+1]); }
  if (tid<100){ tavL[tid]=tav[tid]; avL[tid]=av[tid]; }
  for (int i=tid;i<500;i+=512) aw3L[i]=aw3[i];
  if (tid<5)   prevL[tid]=0.f;
  if (tid<200) elL[tid]=ws[OFF_ENC + 2047*200 + tid];
  __syncthreads();

  // h0,c0 (replicated)
  if (tid<400){
    float zz = ws[OFF_TGW + 63*400 + tid] + ws[OFF_PEW + tid];
    #pragma unroll
    for (int i=0;i<100;i++){ unsigned u=wihc[i]; zz += elL[2*i]*blo(u) + elL[2*i+1]*bhi(u); }
    zpreL[tid]=zz;
  }
  __syncthreads();
  if (tid<100){
    float zi=zpreL[tid], zf=zpreL[tid+100], zg=zpreL[tid+200], zo=zpreL[tid+300];
    float cc = sigf(zi)*tanhfast(zg);
    cL[tid]=cc;
    hL[tid]=sigf(zo)*tanhfast(cc);
  }
  __syncthreads();

  for (int t=0; t<steps; ++t){
    const int p = t&1;
    const int tm = t & (TLEN-1);
    const unsigned seq = (unsigned)(t+1);
    unsigned long long* slot = REC + (size_t)p*GW*RECW;

    // A: tsa[k] = state · tag_attn_w2[k]
    if (tid<400){
      int k=tid>>2, off=(tid&3)*50;
      const float* sb = (off<100)? (hL+off) : (cL+(off-100));
      float acc=0.f;
      #pragma unroll
      for (int i=0;i<25;i++){ unsigned u=tw2r[i]; acc += sb[2*i]*blo(u) + sb[2*i+1]*bhi(u); }
      acc += __shfl_xor(acc,1,4); acc += __shfl_xor(acc,2,4);
      if ((tid&3)==0) tsaL[k]=acc;
    }
    __syncthreads();
    { // B: tag scores
      int sp=tid>>3, l=tid&7;
      float acc=0.f;
      for (int k=l;k<100;k+=8){
        unsigned u=tw1L[sp*50+(k>>1)];
        float w1v=(l&1)? bhi(u) : blo(u);
        acc += tanhfast(w1v + tsaL[k]) * tavL[k];
      }
      acc += __shfl_xor(acc,1,8); acc += __shfl_xor(acc,2,8); acc += __shfl_xor(acc,4,8);
      if (l==0) uL[sp]=acc;
    }
    __syncthreads();
    if (tid<64){ // C: tag softmax
      float v=uL[tid], m=v;
      for (int d=1;d<64;d<<=1) m=fmaxf(m,__shfl_xor(m,d,64));
      float e=__expf(v-m), ssum=e;
      for (int d=1;d<64;d<<=1) ssum+=__shfl_xor(ssum,d,64);
      tawL[tid]=e/ssum;
    }
    __syncthreads();
    if (tid<100){ // D: tag_ctx
      float acc=0.f;
      int h2=tid>>1, par=tid&1;
      #pragma unroll 8
      for (int s=0;s<64;s++){ unsigned u=tagvL[s*50+h2]; acc += tawL[s]*(par? bhi(u):blo(u)); }
      tcL[tid]=acc;
    }
    __syncthreads();
    if (tid<200) nsL[tid] = ((tid<100)? hL[tid] : cL[tid-100]) + tcL[tid%100];
    __syncthreads();
    if (tid<400){ // F: a23[k]
      int k=tid>>2, off=(tid&3)*50;
      float acc=0.f;
      #pragma unroll
      for (int i=0;i<25;i++){ unsigned u=aw2L[k*100+(off>>1)+i]; acc += nsL[off+2*i]*blo(u) + nsL[off+2*i+1]*bhi(u); }
      acc += __shfl_xor(acc,1,4); acc += __shfl_xor(acc,2,4);
      if ((tid&3)==0){
        float a3=0.f;
        #pragma unroll
        for (int i=0;i<5;i++) a3 += prevL[i]*aw3L[k*5+i];
        a23L[k]=acc+a3;
      }
    }
    __syncthreads();
    { // G: own 128 rows' scores (4 lanes/row)
      int r=tid>>2, l=tid&3;
      float acc=0.f;
      #pragma unroll
      for (int k=l;k<100;k+=4){
        unsigned u=w1L[r*50+(k>>1)];
        float w1v=(k&1)? bhi(u) : blo(u);
        acc += tanhfast(w1v + a23L[k]) * avL[k];
      }
      acc += __shfl_xor(acc,1,4); acc += __shfl_xor(acc,2,4);
      if (l==0) srowL[r]=acc;
    }
    __syncthreads();
    if (tid<64){ // G2: local stats + argmax
      float a=srowL[tid], b=srowL[tid+64];
      float bv; int bi;
      if (b>a){ bv=b; bi=w*CHK+tid+64; } else { bv=a; bi=w*CHK+tid; }
      float m=fmaxf(a,b);
      for (int d=1;d<64;d<<=1) m=fmaxf(m,__shfl_xor(m,d,64));
      float ea=__expf(a-m), eb=__expf(b-m);
      eRL[tid]=ea; eRL[tid+64]=eb;
      float Ss=ea+eb;
      for (int d=1;d<64;d<<=1) Ss+=__shfl_xor(Ss,d,64);
      for (int d=1;d<64;d<<=1){
        float ov=__shfl_xor(bv,d,64); int oi=__shfl_xor(bi,d,64);
        if (ov>bv || (ov==bv && oi<bi)){ bv=ov; bi=oi; }
      }
      if (tid==0){ hdrL[0]=m; hdrL[1]=Ss; hdrL[2]=bv; ((int*)hdrL)[3]=bi; }
    }
    __syncthreads();
    if (tid<400){ // G3: ctx partial over own rows
      int d=tid>>1, hf=tid&1;
      int dw=d>>1, par=d&1;
      float acc=0.f;
      #pragma unroll 8
      for (int r2=0;r2<64;r2++){
        int rr=hf*64+r2;
        unsigned u=encL[rr*100+dw];
        acc += eRL[rr]*(par? bhi(u):blo(u));
      }
      acc += __shfl_xor(acc,1,2);
      if (hf==0) ctxpL[d]=acc;
    }
    __syncthreads();
    // H: publish (COMM only)
    if constexpr (COMM){
      unsigned long long* rp = slot + (size_t)w*RECW;
      if (tid<100)            ast64(rp+tid,     mkw(pk2(ctxpL[2*tid],ctxpL[2*tid+1]), seq));
      else if (tid<164){ int i=tid-100; ast64(rp+tid, mkw(pk2(srowL[2*i],srowL[2*i+1]), seq)); }
      else if (tid==164)      ast64(rp+164, mkw(__float_as_uint(hdrL[0]), seq));
      else if (tid==165)      ast64(rp+165, mkw(__float_as_uint(hdrL[1]), seq));
      else if (tid==166)      ast64(rp+166, mkw(__float_as_uint(hdrL[2]), seq));
      else if (tid==167)      ast64(rp+167, mkw((unsigned)((int*)hdrL)[3], seq));
    }
    // E2: zpre = PEW[t] + h@Whh + tag_ctx·Wih_tag   (algebraic replacement of taw@TGW)
    if (tid<400){
      float zz = ws[OFF_PEW + tm*400 + tid];
      #pragma unroll
      for (int i=0;i<50;i++){ unsigned u=whhr[i]; zz += hL[2*i]*blo(u) + hL[2*i+1]*bhi(u); }
      #pragma unroll
      for (int i=0;i<50;i++){ unsigned u=wiht[i]; zz += tcL[2*i]*blo(u) + tcL[2*i+1]*bhi(u); }
      zpreL[tid]=zz;
    }
    // F2: gather (COMM) or local stand-ins (diag)
    if constexpr (COMM){
      int g = tid>>5, l = tid&31;
      const unsigned long long* rp = slot + (size_t)g*RECW;
      const int need3 = (l<4) || (l>=28);
      const int w3 = (l<4)? (96+l) : (136+l);
      unsigned long long v0=0,v1=0,v2=0,v3=0;
      unsigned got=0, want = need3? 0xFu : 0x7u;
      while (got != want){
        if (!(got&1)) v0=ald64(rp+l);
        if (!(got&2)) v1=ald64(rp+32+l);
        if (!(got&4)) v2=ald64(rp+64+l);
        if (need3 && !(got&8)) v3=ald64(rp+w3);
        if ((unsigned)(v0>>32)==seq) got|=1;
        if ((unsigned)(v1>>32)==seq) got|=2;
        if ((unsigned)(v2>>32)==seq) got|=4;
        if (need3 && (unsigned)(v3>>32)==seq) got|=8;
        if (got != want) __builtin_amdgcn_s_sleep(1);
      }
      ctxS[g*100+l]    = (unsigned)v0;
      ctxS[g*100+32+l] = (unsigned)v1;
      ctxS[g*100+64+l] = (unsigned)v2;
      if (l<4)       ctxS[g*100+96+l] = (unsigned)v3;
      else if (l==28) mwL[g]=__uint_as_float((unsigned)v3);
      else if (l==29) SwL[g]=__uint_as_float((unsigned)v3);
      else if (l==30) avvL[g]=__uint_as_float((unsigned)v3);
      else if (l==31) aiL[g]=(int)(unsigned)v3;
    } else {
      if (tid<GW){ mwL[tid]=hdrL[0]; SwL[tid]=hdrL[1]; avvL[tid]=hdrL[2]; aiL[tid]=((int*)hdrL)[3]; }
      for (int i=tid;i<GW*100;i+=512){ int dw=i%100; ctxS[i]=pk2(ctxpL[2*dw], ctxpL[2*dw+1]); }
    }
    __syncthreads();
    if (tid<GW){ // G4: global reduce
      float m=mwL[tid];
      for (int d=1;d<16;d<<=1) m=fmaxf(m,__shfl_xor(m,d,16));
      float sc=__expf(mwL[tid]-m); sclL[tid]=sc;
      float Ss=SwL[tid]*sc;
      for (int d=1;d<16;d<<=1) Ss+=__shfl_xor(Ss,d,16);
      float bv=avvL[tid]; int bi=aiL[tid];
      for (int d=1;d<16;d<<=1){
        float ov=__shfl_xor(bv,d,16); int oi=__shfl_xor(bi,d,16);
        if (ov>bv || (ov==bv && oi<bi)){ bv=ov; bi=oi; }
      }
      if (tid==0){ MS[0]=m; MS[1]=Ss; amiL=bi; }
    }
    __syncthreads();
    // H2a: prev window (5 scores around global argmax)
    if (tid>=440 && tid<445){
      int i=tid-440;
      int st = amiL-1; st = st<0?0:st; st = st>NN-6?NN-6:st;
      int g = st+i;
      float sc;
      if constexpr (COMM){
        int wq = g>>7, wd = 100 + ((g&127)>>1);
        const unsigned long long* pp = slot + (size_t)wq*RECW + wd;
        unsigned long long v = ald64(pp);
        while ((unsigned)(v>>32)!=seq){ __builtin_amdgcn_s_sleep(1); v = ald64(pp); }
        sc = (g&1)? bhi((unsigned)v) : blo((unsigned)v);
      } else {
        sc = srowL[g & (CHK-1)];
      }
      prevL[i] = __expf(sc - MS[0]) / MS[1];
    }
    // H2b: ctx = sum_g scl_g * ctxp_g / S
    if (tid<400){
      float rS = 1.0f/MS[1];
      int dw=tid>>2, s4=tid&3;
      float c0=0.f,c1=0.f;
      #pragma unroll
      for (int i=0;i<4;i++){
        int g=s4*4+i;
        float sc=sclL[g];
        unsigned u=ctxS[g*100+dw];
        c0 += blo(u)*sc; c1 += bhi(u)*sc;
      }
      c0 += __shfl_xor(c0,1,4); c0 += __shfl_xor(c0,2,4);
      c1 += __shfl_xor(c1,1,4); c1 += __shfl_xor(c1,2,4);
      if (s4==0){ ctxL[2*dw]=c0*rS; ctxL[2*dw+1]=c1*rS; }
    }
    __syncthreads();
    if (tid<400){ // I: z = zpre + ctx·Wih_ctx
      float zz=zpreL[tid];
      #pragma unroll
      for (int i=0;i<100;i++){ unsigned u=wihc[i]; zz += ctxL[2*i]*blo(u) + ctxL[2*i+1]*bhi(u); }
      zpreL[tid]=zz;
    }
    __syncthreads();
    if (tid<100){ // J: gates
      float zi=zpreL[tid], zf=zpreL[tid+100], zg=zpreL[tid+200], zo=zpreL[tid+300];
      float cc = sigf(zf)*cL[tid] + sigf(zi)*tanhfast(zg);
      float hh = sigf(zo)*tanhfast(cc);
      cL[tid]=cc; hL[tid]=hh;
      if (w==0) hout[tm*100 + tid] = hh;
    }
    __syncthreads();
  }
}

// ---------------- kLoss: parallel logits + log-softmax over V ----------------
__global__ __launch_bounds__(256) void kLoss(const float* outW, const float* outb,
                                             const int* oid, float* ws)
{
  const int b=blockIdx.x, tid=threadIdx.x;
  const int tile=b>>1, hf=b&1, t0=tile*16;
  __shared__ float s_hn[16*100];
  __shared__ int   s_oid[16];
  __shared__ float red[4][16][3];
  for (int i=tid;i<1600;i+=256) s_hn[i]=ws[OFF_HOUT + t0*100 + i];
  if (tid<16) s_oid[tid]=oid[t0+tid];
  __syncthreads();
  const int VSPLIT = 25129;
  int vbeg = hf? VSPLIT : 0;
  int vend = hf? VOC : VSPLIT;
  float rm[16], rs[16], ol[16];
  #pragma unroll
  for (int tt=0;tt<16;tt++){ rm[tt]=-1e30f; rs[tt]=0.f; ol[tt]=-1e30f; }
  for (int v=vbeg+tid; v<vend; v+=256){
    const float4* wr = (const float4*)(outW + (size_t)v*100);
    float acc[16];
    #pragma unroll
    for (int tt=0;tt<16;tt++) acc[tt]=0.f;
    #pragma unroll 5
    for (int q=0;q<25;q++){
      float4 wv = wr[q];
      #pragma unroll
      for (int tt=0;tt<16;tt++){
        float4 hv = *(const float4*)(s_hn + tt*100 + q*4);
        acc[tt] += wv.x*hv.x + wv.y*hv.y + wv.z*hv.z + wv.w*hv.w;
      }
    }
    float bb = outb[v];
    #pragma unroll
    for (int tt=0;tt<16;tt++){
      float lg = acc[tt] + bb;
      if (v == s_oid[tt]) ol[tt] = fmaxf(ol[tt], lg);
      if (lg <= rm[tt]) rs[tt] += __expf(lg - rm[tt]);
      else { rs[tt] = rs[tt]*__expf(rm[tt]-lg) + 1.0f; rm[tt]=lg; }
    }
  }
  int wv2=tid>>6, ln=tid&63;
  #pragma unroll
  for (int tt=0;tt<16;tt++){
    float m=rm[tt], sv=rs[tt], o=ol[tt];
    for (int d=1;d<64;d<<=1){
      float om=__shfl_xor(m,d,64), os=__shfl_xor(sv,d,64), oo=__shfl_xor(o,d,64);
      float M2=fmaxf(m,om);
      sv = sv*__expf(m-M2) + os*__expf(om-M2);
      m=M2; o=fmaxf(o,oo);
    }
    if (ln==0){ red[wv2][tt][0]=m; red[wv2][tt][1]=sv; red[wv2][tt][2]=o; }
  }
  __syncthreads();
  if (tid<16){
    float M=-1e30f;
    for (int q=0;q<4;q++) M=fmaxf(M,red[q][tid][0]);
    float S=0.f, O=-1e30f;
    for (int q=0;q<4;q++){ S += red[q][tid][1]*__expf(red[q][tid][0]-M); O=fmaxf(O,red[q][tid][2]); }
    float* pb = ws + OFF_PB + (((tile*2)+hf)*16 + tid)*4;
    pb[0]=M; pb[1]=S; pb[2]=O;
  }
}

// ---------------- kFinal: combine halves, sum, scale ----------------
__global__ void kFinal(const float* weight, float* ws, float* out){
  __shared__ float red[256];
  int tid=threadIdx.x;
  float acc=0.f;
  for (int t=tid;t<TLEN;t+=256){
    int tile=t>>4, tt=t&15;
    const float* p0 = ws + OFF_PB + ((tile*2+0)*16+tt)*4;
    const float* p1 = ws + OFF_PB + ((tile*2+1)*16+tt)*4;
    float M=fmaxf(p0[0],p1[0]);
    float S=p0[1]*__expf(p0[0]-M) + p1[1]*__expf(p1[0]-M);
    float O=fmaxf(p0[2],p1[2]);
    acc += (M + logf(S)) - O;
  }
  red[tid]=acc; __syncthreads();
  for (int d=128; d>0; d>>=1){
    if (tid<d) red[tid]+=red[tid+d];
    __syncthreads();
  }
  if (tid==0) out[0]=red[0]*weight[0];
}

// ---------------- launch ----------------
extern "C" void kernel_launch(void* const* d_in, const int* in_sizes, int n_in,
                              void* d_out, int out_size, void* d_ws, size_t ws_size,
                              hipStream_t stream) {
  const int*   src      = (const int*)  d_in[0];
  const int*   tag      = (const int*)  d_in[1];
  const int*   oid      = (const int*)  d_in[2];
  const float* weight   = (const float*)d_in[3];
  const float* emb_char = (const float*)d_in[4];
  const float* emb_tag  = (const float*)d_in[5];
  const float* fWih=(const float*)d_in[6],  *fWhh=(const float*)d_in[7],  *fb=(const float*)d_in[8];
  const float* bWih=(const float*)d_in[9],  *bWhh=(const float*)d_in[10], *bb=(const float*)d_in[11];
  const float* tWih=(const float*)d_in[12], *tWhh=(const float*)d_in[13], *tb=(const float*)d_in[14];
  const float* dWih=(const float*)d_in[15], *dWhh=(const float*)d_in[16], *db=(const float*)d_in[17];
  const float* aw1 =(const float*)d_in[18], *aw2=(const float*)d_in[19];
  const float* aw3 =(const float*)d_in[20], *av =(const float*)d_in[21];
  const float* taw1=(const float*)d_in[22], *taw2=(const float*)d_in[23], *tavv=(const float*)d_in[24];
  const float* outW=(const float*)d_in[25], *outb=(const float*)d_in[26];
  float* ws  = (float*)d_ws;
  float* out = (float*)d_out;

  kInit<<<(2*GW*RECW+255)/256, 256, 0, stream>>>(ws);
  kPrep<<<2*NN+TTAG+TLEN, 512, 0, stream>>>(src,tag,oid,emb_char,emb_tag,
                                            fWih,fb,bWih,bb,tWih,tb,dWih,db,ws);
  kEnc<<<3,512,0,stream>>>(fWhh,bWhh,tWhh,taw1,dWih,ws);
  kMid<<<NN,128,0,stream>>>(aw1,ws);

  // ---- diagnostics (separate dispatches; read via rocprof durations) ----
  kDiagComm<0><<<GW,64,0,stream>>>(ws, DIAG_T, 0);      // plain sys ld/st sync cost
  kDiagComm<1><<<GW,64,0,stream>>>(ws, DIAG_T, 2048);   // RMW-publish sync cost
  kDec<0><<<GW,512,0,stream>>>(dWhh,dWih,aw2,aw3,av,taw2,tavv,ws, DIAG_T); // compute-only

  // ---- real pipeline ----
  kDec<1><<<GW,512,0,stream>>>(dWhh,dWih,aw2,aw3,av,taw2,tavv,ws, TLEN);
  kLoss<<<256,256,0,stream>>>(outW,outb,oid,ws);
  kFinal<<<1,256,0,stream>>>(weight,ws,out);
}

// Round 7
// 36521.136 us; speedup vs baseline: 10.2942x; 10.2942x over previous
//
#include <hip/hip_runtime.h>
#include <math.h>

// ---------------- problem sizes ----------------
#define NN   2048   // source length
#define TLEN 2048   // target length
#define TTAG 64     // tags
#define VOC  50257
#define GW   32     // decoder blocks; each owns CHK source rows + 3-4 hidden units
#define CHK  64     // source rows per block
#define RECW 144    // u64 words per main record slot
static_assert(GW * CHK == NN, "chunking");

// ---------------- workspace layout (float units) ----------------
#define OFF_XF    0                          // NN*400
#define OFF_XB    (OFF_XF  + NN*400)         // NN*400
#define OFF_TGX   (OFF_XB  + NN*400)         // TTAG*400
#define OFF_PEW   (OFF_TGX + TTAG*400)       // TLEN*400
#define OFF_ENC   (OFF_PEW + TLEN*400)       // NN*200
#define OFF_W1DT  (OFF_ENC + NN*200)         // NN*100
#define OFF_TAGV  (OFF_W1DT+ NN*100)         // TTAG*100
#define OFF_TGW1  (OFF_TAGV+ TTAG*100)       // TTAG*100
#define OFF_TGW   (OFF_TGW1+ TTAG*100)       // TTAG*400
#define OFF_HOUT  (OFF_TGW + TTAG*400)       // TLEN*100
#define OFF_REC   (OFF_HOUT+ TLEN*100)       // 2*GW*RECW u64 main records
#define OFF_HC    (OFF_REC + 2*GW*RECW*2)    // 2*256 u64 h/c exchange
#define OFF_PB    (OFF_HC  + 2*256*2)        // loss partials

// main record u64 words: [0..99] ctxp bf16-pairs, [100..131] score bf16-pairs (64 rows),
//   [132] m(f32) [133] S(f32) [134] amax val(f32) [135] amax idx(i32)
// hc buffer b (tag&1): word u*2=h[u](f32), u*2+1=c[u](f32)
// every u64 = {payload u32 lo, seq u32 hi} -> single-word atomicity, no fences

// ---------------- helpers ----------------
__device__ __forceinline__ float rcpf(float x){ return __builtin_amdgcn_rcpf(x); }
__device__ __forceinline__ float sigf(float x){ return rcpf(1.0f+__expf(-x)); }
__device__ __forceinline__ float tanhfast(float x){
  float e = __expf(2.0f*x);
  return 1.0f - 2.0f*rcpf(e+1.0f);
}
__device__ __forceinline__ unsigned short f2b(float x){
  unsigned b=__float_as_uint(x);
  return (unsigned short)((b + 0x7fffu + ((b>>16)&1u))>>16);
}
__device__ __forceinline__ unsigned pk2(float a,float b){ return (unsigned)f2b(a) | ((unsigned)f2b(b)<<16); }
__device__ __forceinline__ float blo(unsigned u){ return __uint_as_float(u<<16); }
__device__ __forceinline__ float bhi(unsigned u){ return __uint_as_float(u&0xffff0000u); }

__device__ __forceinline__ unsigned long long ald64(const unsigned long long* p){
  return __hip_atomic_load(p,__ATOMIC_RELAXED,__HIP_MEMORY_SCOPE_SYSTEM);
}
__device__ __forceinline__ void ast64(unsigned long long* p, unsigned long long v){
  __hip_atomic_store(p,v,__ATOMIC_RELAXED,__HIP_MEMORY_SCOPE_SYSTEM);
}
__device__ __forceinline__ unsigned long long mkw(unsigned pay, unsigned seq){
  return (unsigned long long)pay | ((unsigned long long)seq<<32);
}

// ---------------- kInit: zero record + hc regions ----------------
__global__ void kInit(float* ws){
  unsigned long long* r = (unsigned long long*)(ws + OFF_REC);
  int i = blockIdx.x*256 + threadIdx.x;
  if (i < 2*GW*RECW + 512) ast64(r+i, 0ull);
}

// ---------------- kPrep: all input-side GEMVs (parallel) ----------------
__global__ __launch_bounds__(512) void kPrep(
    const int* src, const int* tag, const int* oid,
    const float* emb_char, const float* emb_tag,
    const float* fWih, const float* fb,
    const float* bWih, const float* bb,
    const float* tWih, const float* tb,
    const float* dWih, const float* db, float* ws)
{
  int r = blockIdx.x, j = threadIdx.x;
  if (j >= 400) return;
  if (r < NN) {
    const float* e = emb_char + (size_t)src[r]*32;
    const float* Wr = fWih + j*32;
    float a = fb[j];
    #pragma unroll
    for (int q=0;q<32;q++) a += e[q]*Wr[q];
    ws[OFF_XF + r*400 + j] = a;
  } else if (r < 2*NN) {
    int n = r - NN;
    const float* e = emb_char + (size_t)src[n]*32;
    const float* Wr = bWih + j*32;
    float a = bb[j];
    #pragma unroll
    for (int q=0;q<32;q++) a += e[q]*Wr[q];
    ws[OFF_XB + n*400 + j] = a;
  } else if (r < 2*NN + TTAG) {
    int s = r - 2*NN;
    const float* e = emb_tag + (size_t)tag[s]*32;
    const float* Wr = tWih + j*32;
    float a = tb[j];
    #pragma unroll
    for (int q=0;q<32;q++) a += e[q]*Wr[q];
    ws[OFF_TGX + s*400 + j] = a;
  } else {
    int t = r - (2*NN + TTAG);
    int pid = (t==0) ? 0 : oid[t-1];
    const float* e = emb_char + (size_t)pid*32;
    const float* Wr = dWih + (size_t)j*332 + 300;
    float a = db[j];
    #pragma unroll
    for (int q=0;q<32;q++) a += e[q]*Wr[q];
    ws[OFF_PEW + t*400 + j] = a;
  }
}

// ---------------- kEnc: sequential LSTM scans (3 independent blocks) ----------------
struct EncShared {
  float tvs[TTAG*100];
  float sa [TTAG*64];
  float hbuf[100];
  float zbuf[400];
};

__device__ void lstm_block(const float* Whh, const float* xbase, float* ws,
                           int reverse, int col, EncShared* sh)
{
  int tid = threadIdx.x;
  float whh[100];
  if (tid < 400){
    #pragma unroll
    for (int k=0;k<100;k++) whh[k] = Whh[tid*100+k];
  }
  float c = 0.f;
  if (tid < 100) sh->hbuf[tid] = 0.f;
  __syncthreads();
  for (int i=0;i<NN;i++){
    int n = reverse ? (NN-1-i) : i;
    if (tid < 400){
      float z = xbase[n*400+tid];
      #pragma unroll 10
      for (int k=0;k<100;k++) z += whh[k]*sh->hbuf[k];
      sh->zbuf[tid] = z;
    }
    __syncthreads();
    if (tid < 100){
      float zi=sh->zbuf[tid], zf=sh->zbuf[tid+100], zg=sh->zbuf[tid+200], zo=sh->zbuf[tid+300];
      c = sigf(zf)*c + sigf(zi)*tanhfast(zg);
      float h = sigf(zo)*tanhfast(c);
      sh->hbuf[tid] = h;
      ws[OFF_ENC + n*200 + col + tid] = h;
    }
    __syncthreads();
  }
}

__global__ __launch_bounds__(512,1) void kEnc(
    const float* fWhh, const float* bWhh, const float* tWhh,
    const float* taw1, const float* dWih, float* ws)
{
  __shared__ EncShared sh;
  int b = blockIdx.x, tid = threadIdx.x;
  if (b == 0){ lstm_block(fWhh, ws+OFF_XF, ws, 0, 0,   &sh); return; }
  if (b == 1){ lstm_block(bWhh, ws+OFF_XB, ws, 1, 100, &sh); return; }

  // ---- block 2: tag LSTM + self-attn + tagv-derived tables ----
  {
    float whh[100];
    if (tid<400){
      #pragma unroll
      for (int k=0;k<100;k++) whh[k] = tWhh[tid*100+k];
    }
    float c = 0.f;
    if (tid<100) sh.hbuf[tid] = 0.f;
    __syncthreads();
    for (int s=0;s<TTAG;s++){
      if (tid<400){
        float z = ws[OFF_TGX + s*400 + tid];
        #pragma unroll 10
        for (int k=0;k<100;k++) z += whh[k]*sh.hbuf[k];
        sh.zbuf[tid] = z;
      }
      __syncthreads();
      if (tid<100){
        float zi=sh.zbuf[tid], zf=sh.zbuf[tid+100], zg=sh.zbuf[tid+200], zo=sh.zbuf[tid+300];
        c = sigf(zf)*c + sigf(zi)*tanhfast(zg);
        float h = sigf(zo)*tanhfast(c);
        sh.hbuf[tid] = h;
        sh.tvs[s*100+tid] = h;
      }
      __syncthreads();
    }
  }
  for (int idx=tid; idx<TTAG*TTAG; idx+=512){
    int s=idx>>6, t2=idx&63;
    float a=0.f;
    #pragma unroll 10
    for (int h=0;h<100;h++) a += sh.tvs[s*100+h]*sh.tvs[t2*100+h];
    sh.sa[idx]=a;
  }
  __syncthreads();
  if (tid<TTAG){
    float m=-1e30f;
    for (int t2=0;t2<64;t2++) m = fmaxf(m, sh.sa[tid*64+t2]);
    float sum=0.f;
    for (int t2=0;t2<64;t2++){ float e=__expf(sh.sa[tid*64+t2]-m); sh.sa[tid*64+t2]=e; sum+=e; }
    float r=1.f/sum;
    for (int t2=0;t2<64;t2++) sh.sa[tid*64+t2]*=r;
  }
  __syncthreads();
  float tvloc[13]; int cnt=0;
  for (int idx=tid; idx<TTAG*100; idx+=512){
    int t2=idx/100, hh=idx%100;
    float a = sh.tvs[t2*100+hh];
    for (int s=0;s<64;s++) a += sh.tvs[s*100+hh]*sh.sa[s*64+t2];
    tvloc[cnt++]=a;
    ws[OFF_TAGV+idx]=a;
  }
  __syncthreads();
  float* tagvs = sh.sa;
  cnt=0;
  for (int idx=tid; idx<TTAG*100; idx+=512) tagvs[idx]=tvloc[cnt++];
  __syncthreads();
  for (int idx=tid; idx<TTAG*100; idx+=512){
    int s=idx/100, k=idx%100;
    float a=0.f;
    #pragma unroll 10
    for (int h=0;h<100;h++) a += tagvs[s*100+h]*taw1[k*100+h];
    ws[OFF_TGW1+idx]=a;
  }
  for (int idx=tid; idx<TTAG*400; idx+=512){
    int s=idx/400, j=idx%400;
    const float* Wr = dWih + (size_t)j*332 + 200;
    float a=0.f;
    #pragma unroll 10
    for (int h=0;h<100;h++) a += tagvs[s*100+h]*Wr[h];
    ws[OFF_TGW+idx]=a;
  }
}

// ---------------- kMid: w1dt = enc @ attn_w1.T ----------------
__global__ void kMid(const float* aw1, float* ws){
  __shared__ float er[200];
  int n=blockIdx.x, tid=threadIdx.x;
  for (int i=tid;i<200;i+=128) er[i]=ws[OFF_ENC+n*200+i];
  __syncthreads();
  if (tid<100){
    const float* Wr = aw1 + tid*200;
    float a=0.f;
    #pragma unroll 8
    for (int d=0;d<200;d++) a += er[d]*Wr[d];
    ws[OFF_W1DT + n*100 + tid]=a;
  }
}

// ---------------- kDec: de-replicated decoder, 32 blocks, 2 hops/step ----------------
__global__ __launch_bounds__(512) void kDec(
    const float* dWhh, const float* dWih,
    const float* aw2, const float* aw3, const float* av,
    const float* taw2, const float* tav, float* ws)
{
  __shared__ unsigned aw2L[100*100];   // attn_w2 bf16 pairs       40.0 KB
  __shared__ unsigned tw2L[100*100];   // tag_attn_w2 bf16 pairs   40.0 KB
  __shared__ unsigned tw1L[TTAG*50];   // tag_w1dt bf16 pairs      12.8 KB
  __shared__ unsigned tagvL[TTAG*50];  // tagv bf16 pairs          12.8 KB
  __shared__ unsigned w1L[CHK*50];     // own w1dt bf16 pairs      12.8 KB
  __shared__ unsigned encL[CHK*100];   // own enc bf16 pairs       25.6 KB
  __shared__ float tavL[100], avL[100], aw3L[500];
  __shared__ float hL[100], cL[100], tcL[100], tsaL[100], nsL[200];
  __shared__ float uL[TTAG], tawL[TTAG];
  __shared__ float ctxL[200], a23L[100], ctxpL[200];
  __shared__ float srowL[CHK], eRL[CHK];
  __shared__ float mwL[GW], SwL[GW], avvL[GW], sclL[GW];
  __shared__ int   aiL[GW];
  __shared__ float zOwnL[16];
  __shared__ float hdrL[4];
  __shared__ float prevL[5];
  __shared__ float MS[2];
  __shared__ int   amiL;

  const int tid = threadIdx.x;
  const int w   = blockIdx.x;
  unsigned long long* REC = (unsigned long long*)(ws + OFF_REC);
  unsigned long long* HC  = (unsigned long long*)(ws + OFF_HC);

  // ---- hidden-unit ownership: blocks 0..3 -> 4 units, 4..31 -> 3 units ----
  const int nu = (w<4)? 4 : 3;
  const int u0 = (w<4)? w*4 : 16 + (w-4)*3;
  const int nact = nu*4;
  const int jslot = tid>>5, l = tid&31;

  // ---- tiny per-thread weight registers (own gate-rows only; ~7 u32) ----
  unsigned wca0=0,wca1=0,wca2=0,wca3=0, wha0=0,wha1=0, wta0=0,wta1=0;
  int row=0;
  if (jslot < nact){
    row = (jslot&3)*100 + u0 + (jslot>>2);
    const float* Wr = dWih + (size_t)row*332;
    wca0=pk2(Wr[2*l],Wr[2*l+1]);
    wca1=pk2(Wr[2*(32+l)],Wr[2*(32+l)+1]);
    wca2=pk2(Wr[2*(64+l)],Wr[2*(64+l)+1]);
    if (l<4) wca3=pk2(Wr[2*(96+l)],Wr[2*(96+l)+1]);
    const float* Wh = dWhh + (size_t)row*100;
    wha0=pk2(Wh[2*l],Wh[2*l+1]);
    if (l<18) wha1=pk2(Wh[2*(32+l)],Wh[2*(32+l)+1]);
    const float* Wt = Wr + 200;
    wta0=pk2(Wt[2*l],Wt[2*l+1]);
    if (l<18) wta1=pk2(Wt[2*(32+l)],Wt[2*(32+l)+1]);
  }
  // ---- LDS preload ----
  for (int i=tid;i<100*100;i+=512){ int k=i/100,p=i%100; aw2L[i]=pk2(aw2 [k*200+2*p], aw2 [k*200+2*p+1]); }
  for (int i=tid;i<100*100;i+=512){ int k=i/100,p=i%100; tw2L[i]=pk2(taw2[k*200+2*p], taw2[k*200+2*p+1]); }
  for (int i=tid;i<TTAG*50;i+=512){ int s=i/50,p=i%50; tw1L[i]=pk2(ws[OFF_TGW1+s*100+2*p], ws[OFF_TGW1+s*100+2*p+1]); }
  for (int i=tid;i<TTAG*50;i+=512){ int s=i/50,p=i%50; tagvL[i]=pk2(ws[OFF_TAGV+s*100+2*p], ws[OFF_TAGV+s*100+2*p+1]); }
  for (int i=tid;i<CHK*50;i+=512){ int r=i/50,p=i%50; w1L[i]=pk2(ws[OFF_W1DT+(w*CHK+r)*100+2*p], ws[OFF_W1DT+(w*CHK+r)*100+2*p+1]); }
  for (int i=tid;i<CHK*100;i+=512){ int r=i/100,p=i%100; encL[i]=pk2(ws[OFF_ENC+(w*CHK+r)*200+2*p], ws[OFF_ENC+(w*CHK+r)*200+2*p+1]); }
  if (tid<100){ tavL[tid]=tav[tid]; avL[tid]=av[tid]; }
  for (int i=tid;i<500;i+=512) aw3L[i]=aw3[i];
  if (tid<5)   prevL[tid]=0.f;
  if (tid<200) ctxL[tid]=ws[OFF_ENC + 2047*200 + tid];   // enc_last for init
  __syncthreads();

  // ---- init: own-row z0 -> h0,c0 -> publish hc tag 1 (buffer 1) ----
  if (jslot < nact){
    float acc=0.f;
    { unsigned u=wca0; acc += ctxL[2*l]*blo(u) + ctxL[2*l+1]*bhi(u); }
    { unsigned u=wca1; acc += ctxL[2*(32+l)]*blo(u) + ctxL[2*(32+l)+1]*bhi(u); }
    { unsigned u=wca2; acc += ctxL[2*(64+l)]*blo(u) + ctxL[2*(64+l)+1]*bhi(u); }
    if (l<4){ unsigned u=wca3; acc += ctxL[2*(96+l)]*blo(u) + ctxL[2*(96+l)+1]*bhi(u); }
    acc += __shfl_xor(acc,1,32); acc += __shfl_xor(acc,2,32);
    acc += __shfl_xor(acc,4,32); acc += __shfl_xor(acc,8,32); acc += __shfl_xor(acc,16,32);
    if (l==0) zOwnL[jslot] = acc + ws[OFF_TGW + 63*400 + row] + ws[OFF_PEW + row];
  }
  __syncthreads();
  if (tid < nu){
    float zi=zOwnL[tid*4+0], zf=zOwnL[tid*4+1], zg=zOwnL[tid*4+2], zo=zOwnL[tid*4+3];
    (void)zf;
    float cc = sigf(zi)*tanhfast(zg);
    float hh = sigf(zo)*tanhfast(cc);
    int u = u0+tid;
    unsigned long long* hb = HC + 256;   // tag1 -> buffer 1
    ast64(hb+u*2+0, mkw(__float_as_uint(hh), 1u));
    ast64(hb+u*2+1, mkw(__float_as_uint(cc), 1u));
  }

  for (int t=0; t<TLEN; ++t){
    const unsigned sq = (unsigned)(t+1);
    unsigned long long* slot = REC + (size_t)(t&1)*GW*RECW;
    unsigned long long* hcg  = HC + (size_t)((t+1)&1)*256;  // gather tag t+1
    unsigned long long* hcp  = HC + (size_t)(t&1)*256;      // publish tag t+2

    // 1: gather full h,c (state entering step t)
    if (tid<200){
      const unsigned long long* pp = hcg + tid;
      unsigned long long v = ald64(pp);
      while ((unsigned)(v>>32)!=sq){ __builtin_amdgcn_s_sleep(1); v=ald64(pp); }
      float f = __uint_as_float((unsigned)v);
      if (tid&1) cL[tid>>1]=f; else hL[tid>>1]=f;
    }
    __syncthreads();
    // 2: tsa[k] = state · tag_attn_w2[k]   (4 thr/k, LDS weights)
    if (tid<400){
      int k=tid>>2, q=tid&3, off=q*50;
      const float* sb = (off<100)? (hL+off) : (cL+(off-100));
      float acc=0.f;
      #pragma unroll
      for (int i=0;i<25;i++){ unsigned u=tw2L[k*100+q*25+i]; acc += sb[2*i]*blo(u) + sb[2*i+1]*bhi(u); }
      acc += __shfl_xor(acc,1,4); acc += __shfl_xor(acc,2,4);
      if (q==0) tsaL[k]=acc;
    }
    __syncthreads();
    { // 3: tag scores u[s'] (8 thr/tag)
      int sp=tid>>3, l8=tid&7;
      float acc=0.f;
      for (int k=l8;k<100;k+=8){
        unsigned u=tw1L[sp*50+(k>>1)];
        float w1v=(k&1)? bhi(u) : blo(u);
        acc += tanhfast(w1v + tsaL[k]) * tavL[k];
      }
      acc += __shfl_xor(acc,1,8); acc += __shfl_xor(acc,2,8); acc += __shfl_xor(acc,4,8);
      if (l8==0) uL[sp]=acc;
    }
    __syncthreads();
    if (tid<64){ // 4: softmax over 64 tags
      float v=uL[tid], m=v;
      for (int d=1;d<64;d<<=1) m=fmaxf(m,__shfl_xor(m,d,64));
      float e=__expf(v-m), ssum=e;
      for (int d=1;d<64;d<<=1) ssum+=__shfl_xor(ssum,d,64);
      tawL[tid]=e*rcpf(ssum);
    }
    __syncthreads();
    if (tid<400){ // 5: tag_ctx (4 thr/hh)
      int hh=tid>>2, q=tid&3;
      float acc=0.f;
      #pragma unroll
      for (int i=0;i<16;i++){
        int s=q*16+i;
        unsigned u=tagvL[s*50+(hh>>1)];
        acc += tawL[s]*((hh&1)? bhi(u):blo(u));
      }
      acc += __shfl_xor(acc,1,4); acc += __shfl_xor(acc,2,4);
      if (q==0) tcL[hh]=acc;
    }
    __syncthreads();
    if (tid<200) nsL[tid] = ((tid<100)? hL[tid] : cL[tid-100]) + tcL[tid%100];
    __syncthreads();
    if (tid<400){ // 6: a23[k]
      int k=tid>>2, q=tid&3, off=q*50;
      float acc=0.f;
      #pragma unroll
      for (int i=0;i<25;i++){ unsigned u=aw2L[k*100+q*25+i]; acc += nsL[off+2*i]*blo(u) + nsL[off+2*i+1]*bhi(u); }
      acc += __shfl_xor(acc,1,4); acc += __shfl_xor(acc,2,4);
      if (q==0){
        float a3=0.f;
        #pragma unroll
        for (int i=0;i<5;i++) a3 += prevL[i]*aw3L[k*5+i];
        a23L[k]=acc+a3;
      }
    }
    __syncthreads();
    { // 7: own 64 rows' scores (8 lanes/row)
      int r=tid>>3, l8=tid&7;
      float acc=0.f;
      for (int k=l8;k<100;k+=8){
        unsigned u=w1L[r*50+(k>>1)];
        float w1v=(k&1)? bhi(u) : blo(u);
        acc += tanhfast(w1v + a23L[k]) * avL[k];
      }
      acc += __shfl_xor(acc,1,8); acc += __shfl_xor(acc,2,8); acc += __shfl_xor(acc,4,8);
      if (l8==0) srowL[r]=acc;
    }
    __syncthreads();
    if (tid<64){ // 8: local stats + argmax over own 64 rows
      float v=srowL[tid], m=v;
      for (int d=1;d<64;d<<=1) m=fmaxf(m,__shfl_xor(m,d,64));
      float e=__expf(v-m); eRL[tid]=e;
      float Ss=e;
      for (int d=1;d<64;d<<=1) Ss+=__shfl_xor(Ss,d,64);
      float bv=v; int bi=w*CHK+tid;
      for (int d=1;d<64;d<<=1){
        float ov=__shfl_xor(bv,d,64); int oi=__shfl_xor(bi,d,64);
        if (ov>bv || (ov==bv && oi<bi)){ bv=ov; bi=oi; }
      }
      if (tid==0){ hdrL[0]=m; hdrL[1]=Ss; hdrL[2]=bv; ((int*)hdrL)[3]=bi; }
    }
    __syncthreads();
    if (tid<400){ // 9: ctx partial over own rows (2 thr/d)
      int d=tid>>1, hf=tid&1;
      float acc=0.f;
      #pragma unroll 8
      for (int i=0;i<32;i++){
        int rr=hf*32+i;
        unsigned u=encL[rr*100+(d>>1)];
        acc += eRL[rr]*((d&1)? bhi(u):blo(u));
      }
      acc += __shfl_xor(acc,1,2);
      if (hf==0) ctxpL[d]=acc;
    }
    __syncthreads();
    // 10: publish-1 (ctxp + scores + hdr), seq-embedded words
    {
      unsigned long long* rp = slot + (size_t)w*RECW;
      if (tid<100)            ast64(rp+tid,     mkw(pk2(ctxpL[2*tid],ctxpL[2*tid+1]), sq));
      else if (tid<132){ int i=tid-100; ast64(rp+tid, mkw(pk2(srowL[2*i],srowL[2*i+1]), sq)); }
      else if (tid==132)      ast64(rp+132, mkw(__float_as_uint(hdrL[0]), sq));
      else if (tid==133)      ast64(rp+133, mkw(__float_as_uint(hdrL[1]), sq));
      else if (tid==134)      ast64(rp+134, mkw(__float_as_uint(hdrL[2]), sq));
      else if (tid==135)      ast64(rp+135, mkw((unsigned)((int*)hdrL)[3], sq));
    }
    // 11: own-row zpre = PEW[t] + h@Whh + tc@Wiht (overlaps publish propagation)
    if (jslot < nact){
      float acc=0.f;
      { unsigned u=wha0; acc += hL[2*l]*blo(u) + hL[2*l+1]*bhi(u); }
      if (l<18){ unsigned u=wha1; acc += hL[2*(32+l)]*blo(u) + hL[2*(32+l)+1]*bhi(u); }
      { unsigned u=wta0; acc += tcL[2*l]*blo(u) + tcL[2*l+1]*bhi(u); }
      if (l<18){ unsigned u=wta1; acc += tcL[2*(32+l)]*blo(u) + tcL[2*(32+l)+1]*bhi(u); }
      acc += __shfl_xor(acc,1,32); acc += __shfl_xor(acc,2,32);
      acc += __shfl_xor(acc,4,32); acc += __shfl_xor(acc,8,32); acc += __shfl_xor(acc,16,32);
      if (l==0) zOwnL[jslot] = acc + ws[OFF_PEW + t*400 + row];
    }
    // 12: gather-1 — thr<400: 8 ctx words (same dw across recs); thr>=448: hdr
    unsigned pay[8];
    if (tid<400){
      const int dw=tid>>2, s4=tid&3;
      unsigned got=0;
      unsigned long long v[8];
      while (got != 0xFFu){
        #pragma unroll
        for (int i=0;i<8;i++) if(!((got>>i)&1)) v[i]=ald64(slot + (size_t)(s4*8+i)*RECW + dw);
        #pragma unroll
        for (int i=0;i<8;i++) if(!((got>>i)&1) && (unsigned)(v[i]>>32)==sq){ pay[i]=(unsigned)v[i]; got|=1u<<i; }
        if (got!=0xFFu) __builtin_amdgcn_s_sleep(1);
      }
    } else if (tid>=448){
      int t2=tid-448, r=t2>>1, p=t2&1;
      const unsigned long long* q0 = slot + (size_t)r*RECW + 132 + 2*p;
      unsigned long long a=ald64(q0), b=ald64(q0+1);
      while ((unsigned)(a>>32)!=sq){ __builtin_amdgcn_s_sleep(1); a=ald64(q0); }
      while ((unsigned)(b>>32)!=sq){ __builtin_amdgcn_s_sleep(1); b=ald64(q0+1); }
      if (p==0){ mwL[r]=__uint_as_float((unsigned)a); SwL[r]=__uint_as_float((unsigned)b); }
      else     { avvL[r]=__uint_as_float((unsigned)a); aiL[r]=(int)(unsigned)b; }
    }
    __syncthreads();
    if (tid<GW){ // 13: global stat + argmax reduce (32 lanes)
      float m=mwL[tid];
      for (int d=1;d<32;d<<=1) m=fmaxf(m,__shfl_xor(m,d,32));
      float sc=__expf(mwL[tid]-m); sclL[tid]=sc;
      float Ss=SwL[tid]*sc;
      for (int d=1;d<32;d<<=1) Ss+=__shfl_xor(Ss,d,32);
      float bv=avvL[tid]; int bi=aiL[tid];
      for (int d=1;d<32;d<<=1){
        float ov=__shfl_xor(bv,d,32); int oi=__shfl_xor(bi,d,32);
        if (ov>bv || (ov==bv && oi<bi)){ bv=ov; bi=oi; }
      }
      if (tid==0){ MS[0]=m; MS[1]=Ss; amiL=bi; }
    }
    __syncthreads();
    // 14a: next-step prev window (5 bf16 scores around global argmax)
    if (tid>=440 && tid<445){
      int i=tid-440;
      int st = amiL-1; st = st<0?0:st; st = st>NN-6?NN-6:st;
      int g = st+i, wq = g>>6, wd = 100 + ((g&63)>>1);
      const unsigned long long* pp = slot + (size_t)wq*RECW + wd;
      unsigned long long v = ald64(pp);
      while ((unsigned)(v>>32)!=sq){ __builtin_amdgcn_s_sleep(1); v=ald64(pp); }
      float sc = (g&1)? bhi((unsigned)v) : blo((unsigned)v);
      prevL[i] = __expf(sc - MS[0]) * rcpf(MS[1]);
    }
    // 14b: ctx assemble from gathered payloads
    if (tid<400){
      float rS = rcpf(MS[1]);
      int dw=tid>>2, s4=tid&3;
      float c0=0.f,c1=0.f;
      #pragma unroll
      for (int i=0;i<8;i++){
        float sc=sclL[s4*8+i];
        c0 += blo(pay[i])*sc; c1 += bhi(pay[i])*sc;
      }
      c0 += __shfl_xor(c0,1,4); c0 += __shfl_xor(c0,2,4);
      c1 += __shfl_xor(c1,1,4); c1 += __shfl_xor(c1,2,4);
      if (s4==0){ ctxL[2*dw]=c0*rS; ctxL[2*dw+1]=c1*rS; }
    }
    __syncthreads();
    // 15: own-row z += ctx·Wihc
    if (jslot < nact){
      float acc=0.f;
      { unsigned u=wca0; acc += ctxL[2*l]*blo(u) + ctxL[2*l+1]*bhi(u); }
      { unsigned u=wca1; acc += ctxL[2*(32+l)]*blo(u) + ctxL[2*(32+l)+1]*bhi(u); }
      { unsigned u=wca2; acc += ctxL[2*(64+l)]*blo(u) + ctxL[2*(64+l)+1]*bhi(u); }
      if (l<4){ unsigned u=wca3; acc += ctxL[2*(96+l)]*blo(u) + ctxL[2*(96+l)+1]*bhi(u); }
      acc += __shfl_xor(acc,1,32); acc += __shfl_xor(acc,2,32);
      acc += __shfl_xor(acc,4,32); acc += __shfl_xor(acc,8,32); acc += __shfl_xor(acc,16,32);
      if (l==0) zOwnL[jslot] += acc;
    }
    __syncthreads();
    // 16: own-unit gates; publish h,c (f32 payloads) tag t+2; write HOUT
    if (tid<nu){
      float zi=zOwnL[tid*4+0], zf=zOwnL[tid*4+1], zg=zOwnL[tid*4+2], zo=zOwnL[tid*4+3];
      int u=u0+tid;
      float cc = sigf(zf)*cL[u] + sigf(zi)*tanhfast(zg);
      float hh = sigf(zo)*tanhfast(cc);
      ast64(hcp+u*2+0, mkw(__float_as_uint(hh), sq+1u));
      ast64(hcp+u*2+1, mkw(__float_as_uint(cc), sq+1u));
      ws[OFF_HOUT + t*100 + u] = hh;
    }
    __syncthreads();
  }
}

// ---------------- kLoss: parallel logits + log-softmax over V ----------------
__global__ __launch_bounds__(256) void kLoss(const float* outW, const float* outb,
                                             const int* oid, float* ws)
{
  const int b=blockIdx.x, tid=threadIdx.x;
  const int tile=b>>1, hf=b&1, t0=tile*16;
  __shared__ float s_hn[16*100];
  __shared__ int   s_oid[16];
  __shared__ float red[4][16][3];
  for (int i=tid;i<1600;i+=256) s_hn[i]=ws[OFF_HOUT + t0*100 + i];
  if (tid<16) s_oid[tid]=oid[t0+tid];
  __syncthreads();
  const int VSPLIT = 25129;
  int vbeg = hf? VSPLIT : 0;
  int vend = hf? VOC : VSPLIT;
  float rm[16], rs[16], ol[16];
  #pragma unroll
  for (int tt=0;tt<16;tt++){ rm[tt]=-1e30f; rs[tt]=0.f; ol[tt]=-1e30f; }
  for (int v=vbeg+tid; v<vend; v+=256){
    const float4* wr = (const float4*)(outW + (size_t)v*100);
    float acc[16];
    #pragma unroll
    for (int tt=0;tt<16;tt++) acc[tt]=0.f;
    #pragma unroll 5
    for (int q=0;q<25;q++){
      float4 wv = wr[q];
      #pragma unroll
      for (int tt=0;tt<16;tt++){
        float4 hv = *(const float4*)(s_hn + tt*100 + q*4);
        acc[tt] += wv.x*hv.x + wv.y*hv.y + wv.z*hv.z + wv.w*hv.w;
      }
    }
    float bb = outb[v];
    #pragma unroll
    for (int tt=0;tt<16;tt++){
      float lg = acc[tt] + bb;
      if (v == s_oid[tt]) ol[tt] = fmaxf(ol[tt], lg);
      if (lg <= rm[tt]) rs[tt] += __expf(lg - rm[tt]);
      else { rs[tt] = rs[tt]*__expf(rm[tt]-lg) + 1.0f; rm[tt]=lg; }
    }
  }
  int wv2=tid>>6, ln=tid&63;
  #pragma unroll
  for (int tt=0;tt<16;tt++){
    float m=rm[tt], sv=rs[tt], o=ol[tt];
    for (int d=1;d<64;d<<=1){
      float om=__shfl_xor(m,d,64), os=__shfl_xor(sv,d,64), oo=__shfl_xor(o,d,64);
      float M2=fmaxf(m,om);
      sv = sv*__expf(m-M2) + os*__expf(om-M2);
      m=M2; o=fmaxf(o,oo);
    }
    if (ln==0){ red[wv2][tt][0]=m; red[wv2][tt][1]=sv; red[wv2][tt][2]=o; }
  }
  __syncthreads();
  if (tid<16){
    float M=-1e30f;
    for (int q=0;q<4;q++) M=fmaxf(M,red[q][tid][0]);
    float S=0.f, O=-1e30f;
    for (int q=0;q<4;q++){ S += red[q][tid][1]*__expf(red[q][tid][0]-M); O=fmaxf(O,red[q][tid][2]); }
    float* pb = ws + OFF_PB + (((tile*2)+hf)*16 + tid)*4;
    pb[0]=M; pb[1]=S; pb[2]=O;
  }
}

// ---------------- kFinal: combine halves, sum, scale ----------------
__global__ void kFinal(const float* weight, float* ws, float* out){
  __shared__ float red[256];
  int tid=threadIdx.x;
  float acc=0.f;
  for (int t=tid;t<TLEN;t+=256){
    int tile=t>>4, tt=t&15;
    const float* p0 = ws + OFF_PB + ((tile*2+0)*16+tt)*4;
    const float* p1 = ws + OFF_PB + ((tile*2+1)*16+tt)*4;
    float M=fmaxf(p0[0],p1[0]);
    float S=p0[1]*__expf(p0[0]-M) + p1[1]*__expf(p1[0]-M);
    float O=fmaxf(p0[2],p1[2]);
    acc += (M + logf(S)) - O;
  }
  red[tid]=acc; __syncthreads();
  for (int d=128; d>0; d>>=1){
    if (tid<d) red[tid]+=red[tid+d];
    __syncthreads();
  }
  if (tid==0) out[0]=red[0]*weight[0];
}

// ---------------- launch ----------------
extern "C" void kernel_launch(void* const* d_in, const int* in_sizes, int n_in,
                              void* d_out, int out_size, void* d_ws, size_t ws_size,
                              hipStream_t stream) {
  const int*   src      = (const int*)  d_in[0];
  const int*   tag      = (const int*)  d_in[1];
  const int*   oid      = (const int*)  d_in[2];
  const float* weight   = (const float*)d_in[3];
  const float* emb_char = (const float*)d_in[4];
  const float* emb_tag  = (const float*)d_in[5];
  const float* fWih=(const float*)d_in[6],  *fWhh=(const float*)d_in[7],  *fb=(const float*)d_in[8];
  const float* bWih=(const float*)d_in[9],  *bWhh=(const float*)d_in[10], *bb=(const float*)d_in[11];
  const float* tWih=(const float*)d_in[12], *tWhh=(const float*)d_in[13], *tb=(const float*)d_in[14];
  const float* dWih=(const float*)d_in[15], *dWhh=(const float*)d_in[16], *db=(const float*)d_in[17];
  const float* aw1 =(const float*)d_in[18], *aw2=(const float*)d_in[19];
  const float* aw3 =(const float*)d_in[20], *av =(const float*)d_in[21];
  const float* taw1=(const float*)d_in[22], *taw2=(const float*)d_in[23], *tavv=(const float*)d_in[24];
  const float* outW=(const float*)d_in[25], *outb=(const float*)d_in[26];
  float* ws  = (float*)d_ws;
  float* out = (float*)d_out;

  kInit<<<(2*GW*RECW+512+255)/256, 256, 0, stream>>>(ws);
  kPrep<<<2*NN+TTAG+TLEN, 512, 0, stream>>>(src,tag,oid,emb_char,emb_tag,
                                            fWih,fb,bWih,bb,tWih,tb,dWih,db,ws);
  kEnc<<<3,512,0,stream>>>(fWhh,bWhh,tWhh,taw1,dWih,ws);
  kMid<<<NN,128,0,stream>>>(aw1,ws);
  kDec<<<GW,512,0,stream>>>(dWhh,dWih,aw2,aw3,av,taw2,tavv,ws);
  kLoss<<<256,256,0,stream>>>(outW,outb,oid,ws);
  kFinal<<<1,256,0,stream>>>(weight,ws,out);
}

// Round 8
// 36115.640 us; speedup vs baseline: 10.4098x; 1.0112x over previous
//
#include <hip/hip_runtime.h>
#include <math.h>

// ---------------- problem sizes ----------------
#define NN   2048   // source length
#define TLEN 2048   // target length
#define TTAG 64     // tags
#define VOC  50257
#define GW   32     // decoder blocks; each owns CHK source rows + 3-4 hidden units
#define CHK  64     // source rows per block
#define RECU 80     // u64 stride per record (68 used)
static_assert(GW * CHK == NN, "chunking");

// ---------------- workspace layout (float units) ----------------
#define OFF_XF    0                          // NN*400
#define OFF_XB    (OFF_XF  + NN*400)         // NN*400
#define OFF_TGX   (OFF_XB  + NN*400)         // TTAG*400
#define OFF_PEW   (OFF_TGX + TTAG*400)       // TLEN*400
#define OFF_ENC   (OFF_PEW + TLEN*400)       // NN*200
#define OFF_W1DT  (OFF_ENC + NN*200)         // NN*100
#define OFF_TAGV  (OFF_W1DT+ NN*100)         // TTAG*100
#define OFF_TGW1  (OFF_TAGV+ TTAG*100)       // TTAG*100
#define OFF_TGW   (OFF_TGW1+ TTAG*100)       // TTAG*400
#define OFF_HOUT  (OFF_TGW + TTAG*400)       // TLEN*100
#define OFF_REC   (OFF_HOUT+ TLEN*100)       // 2*GW*RECU u64 = 10240 floats
#define OFF_HC    (OFF_REC + 2*GW*RECU*2)    // 2*128 u64 = 512 floats
#define OFF_FLG   (OFF_HC  + 2*128*2)        // 2048 u64 flags (128B-spread) = 4096 floats
#define OFF_PB    (OFF_FLG + 4096)           // loss partials

// record u64 words: [0..49] ctxp 4xbf16/word, [50..65] scores 4xbf16/word (64 rows),
//   [66]={m f32 | S f32}, [67]={amax f32 | idx}
// hc buffer b: word u = {h[u] f32 | c[u] f32}
// flags: frec(b,w)=FLG[(b*32+w)*16], fhc(b,w)=FLG[(64+b*32+w)*16]; value = seq.
// Protocol: data stores (system write-through) -> s_waitcnt vmcnt(0) per wave ->
// barrier -> one flag store. Consumer: 32 pollers on flags -> bulk read (no retry).

// ---------------- helpers ----------------
__device__ __forceinline__ float rcpf(float x){ return __builtin_amdgcn_rcpf(x); }
__device__ __forceinline__ float sigf(float x){ return rcpf(1.0f+__expf(-x)); }
__device__ __forceinline__ float tanhfast(float x){
  float e = __expf(2.0f*x);
  return 1.0f - 2.0f*rcpf(e+1.0f);
}
__device__ __forceinline__ unsigned short f2b(float x){
  unsigned b=__float_as_uint(x);
  return (unsigned short)((b + 0x7fffu + ((b>>16)&1u))>>16);
}
__device__ __forceinline__ unsigned pk2(float a,float b){ return (unsigned)f2b(a) | ((unsigned)f2b(b)<<16); }
__device__ __forceinline__ float blo(unsigned u){ return __uint_as_float(u<<16); }
__device__ __forceinline__ float bhi(unsigned u){ return __uint_as_float(u&0xffff0000u); }

__device__ __forceinline__ unsigned long long ald64(const unsigned long long* p){
  return __hip_atomic_load(p,__ATOMIC_RELAXED,__HIP_MEMORY_SCOPE_SYSTEM);
}
__device__ __forceinline__ void ast64(unsigned long long* p, unsigned long long v){
  __hip_atomic_store(p,v,__ATOMIC_RELAXED,__HIP_MEMORY_SCOPE_SYSTEM);
}
__device__ __forceinline__ void vm0(){ asm volatile("s_waitcnt vmcnt(0)" ::: "memory"); }

// ---------------- kInit: zero flag region (every launch / replay) ----------------
__global__ void kInit(float* ws){
  unsigned long long* f = (unsigned long long*)(ws + OFF_FLG);
  int i = blockIdx.x*256 + threadIdx.x;
  if (i < 2048) ast64(f+i, 0ull);
}

// ---------------- kPrep: all input-side GEMVs (parallel) ----------------
__global__ __launch_bounds__(512) void kPrep(
    const int* src, const int* tag, const int* oid,
    const float* emb_char, const float* emb_tag,
    const float* fWih, const float* fb,
    const float* bWih, const float* bb,
    const float* tWih, const float* tb,
    const float* dWih, const float* db, float* ws)
{
  int r = blockIdx.x, j = threadIdx.x;
  if (j >= 400) return;
  if (r < NN) {
    const float* e = emb_char + (size_t)src[r]*32;
    const float* Wr = fWih + j*32;
    float a = fb[j];
    #pragma unroll
    for (int q=0;q<32;q++) a += e[q]*Wr[q];
    ws[OFF_XF + r*400 + j] = a;
  } else if (r < 2*NN) {
    int n = r - NN;
    const float* e = emb_char + (size_t)src[n]*32;
    const float* Wr = bWih + j*32;
    float a = bb[j];
    #pragma unroll
    for (int q=0;q<32;q++) a += e[q]*Wr[q];
    ws[OFF_XB + n*400 + j] = a;
  } else if (r < 2*NN + TTAG) {
    int s = r - 2*NN;
    const float* e = emb_tag + (size_t)tag[s]*32;
    const float* Wr = tWih + j*32;
    float a = tb[j];
    #pragma unroll
    for (int q=0;q<32;q++) a += e[q]*Wr[q];
    ws[OFF_TGX + s*400 + j] = a;
  } else {
    int t = r - (2*NN + TTAG);
    int pid = (t==0) ? 0 : oid[t-1];
    const float* e = emb_char + (size_t)pid*32;
    const float* Wr = dWih + (size_t)j*332 + 300;
    float a = db[j];
    #pragma unroll
    for (int q=0;q<32;q++) a += e[q]*Wr[q];
    ws[OFF_PEW + t*400 + j] = a;
  }
}

// ---------------- kEnc: sequential LSTM scans (3 independent blocks) ----------------
struct EncShared {
  float tvs[TTAG*100];
  float sa [TTAG*64];
  float hbuf[100];
  float zbuf[400];
};

__device__ void lstm_block(const float* Whh, const float* xbase, float* ws,
                           int reverse, int col, EncShared* sh)
{
  int tid = threadIdx.x;
  float whh[100];
  if (tid < 400){
    #pragma unroll
    for (int k=0;k<100;k++) whh[k] = Whh[tid*100+k];
  }
  float c = 0.f;
  if (tid < 100) sh->hbuf[tid] = 0.f;
  __syncthreads();
  for (int i=0;i<NN;i++){
    int n = reverse ? (NN-1-i) : i;
    if (tid < 400){
      float z = xbase[n*400+tid];
      #pragma unroll 10
      for (int k=0;k<100;k++) z += whh[k]*sh->hbuf[k];
      sh->zbuf[tid] = z;
    }
    __syncthreads();
    if (tid < 100){
      float zi=sh->zbuf[tid], zf=sh->zbuf[tid+100], zg=sh->zbuf[tid+200], zo=sh->zbuf[tid+300];
      c = sigf(zf)*c + sigf(zi)*tanhfast(zg);
      float h = sigf(zo)*tanhfast(c);
      sh->hbuf[tid] = h;
      ws[OFF_ENC + n*200 + col + tid] = h;
    }
    __syncthreads();
  }
}

__global__ __launch_bounds__(512,1) void kEnc(
    const float* fWhh, const float* bWhh, const float* tWhh,
    const float* taw1, const float* dWih, float* ws)
{
  __shared__ EncShared sh;
  int b = blockIdx.x, tid = threadIdx.x;
  if (b == 0){ lstm_block(fWhh, ws+OFF_XF, ws, 0, 0,   &sh); return; }
  if (b == 1){ lstm_block(bWhh, ws+OFF_XB, ws, 1, 100, &sh); return; }

  // ---- block 2: tag LSTM + self-attn + tagv-derived tables ----
  {
    float whh[100];
    if (tid<400){
      #pragma unroll
      for (int k=0;k<100;k++) whh[k] = tWhh[tid*100+k];
    }
    float c = 0.f;
    if (tid<100) sh.hbuf[tid] = 0.f;
    __syncthreads();
    for (int s=0;s<TTAG;s++){
      if (tid<400){
        float z = ws[OFF_TGX + s*400 + tid];
        #pragma unroll 10
        for (int k=0;k<100;k++) z += whh[k]*sh.hbuf[k];
        sh.zbuf[tid] = z;
      }
      __syncthreads();
      if (tid<100){
        float zi=sh.zbuf[tid], zf=sh.zbuf[tid+100], zg=sh.zbuf[tid+200], zo=sh.zbuf[tid+300];
        c = sigf(zf)*c + sigf(zi)*tanhfast(zg);
        float h = sigf(zo)*tanhfast(c);
        sh.hbuf[tid] = h;
        sh.tvs[s*100+tid] = h;
      }
      __syncthreads();
    }
  }
  for (int idx=tid; idx<TTAG*TTAG; idx+=512){
    int s=idx>>6, t2=idx&63;
    float a=0.f;
    #pragma unroll 10
    for (int h=0;h<100;h++) a += sh.tvs[s*100+h]*sh.tvs[t2*100+h];
    sh.sa[idx]=a;
  }
  __syncthreads();
  if (tid<TTAG){
    float m=-1e30f;
    for (int t2=0;t2<64;t2++) m = fmaxf(m, sh.sa[tid*64+t2]);
    float sum=0.f;
    for (int t2=0;t2<64;t2++){ float e=__expf(sh.sa[tid*64+t2]-m); sh.sa[tid*64+t2]=e; sum+=e; }
    float r=1.f/sum;
    for (int t2=0;t2<64;t2++) sh.sa[tid*64+t2]*=r;
  }
  __syncthreads();
  float tvloc[13]; int cnt=0;
  for (int idx=tid; idx<TTAG*100; idx+=512){
    int t2=idx/100, hh=idx%100;
    float a = sh.tvs[t2*100+hh];
    for (int s=0;s<64;s++) a += sh.tvs[s*100+hh]*sh.sa[s*64+t2];
    tvloc[cnt++]=a;
    ws[OFF_TAGV+idx]=a;
  }
  __syncthreads();
  float* tagvs = sh.sa;
  cnt=0;
  for (int idx=tid; idx<TTAG*100; idx+=512) tagvs[idx]=tvloc[cnt++];
  __syncthreads();
  for (int idx=tid; idx<TTAG*100; idx+=512){
    int s=idx/100, k=idx%100;
    float a=0.f;
    #pragma unroll 10
    for (int h=0;h<100;h++) a += tagvs[s*100+h]*taw1[k*100+h];
    ws[OFF_TGW1+idx]=a;
  }
  for (int idx=tid; idx<TTAG*400; idx+=512){
    int s=idx/400, j=idx%400;
    const float* Wr = dWih + (size_t)j*332 + 200;
    float a=0.f;
    #pragma unroll 10
    for (int h=0;h<100;h++) a += tagvs[s*100+h]*Wr[h];
    ws[OFF_TGW+idx]=a;
  }
}

// ---------------- kMid: w1dt = enc @ attn_w1.T ----------------
__global__ void kMid(const float* aw1, float* ws){
  __shared__ float er[200];
  int n=blockIdx.x, tid=threadIdx.x;
  for (int i=tid;i<200;i+=128) er[i]=ws[OFF_ENC+n*200+i];
  __syncthreads();
  if (tid<100){
    const float* Wr = aw1 + tid*200;
    float a=0.f;
    #pragma unroll 8
    for (int d=0;d<200;d++) a += er[d]*Wr[d];
    ws[OFF_W1DT + n*100 + tid]=a;
  }
}

// ---------------- kDec: de-replicated decoder, flag+bulk exchange ----------------
__global__ __launch_bounds__(512) void kDec(
    const float* dWhh, const float* dWih,
    const float* aw2, const float* aw3, const float* av,
    const float* taw2, const float* tav, float* ws)
{
  __shared__ unsigned aw2L[100*100];   // attn_w2 bf16 pairs       40.0 KB
  __shared__ unsigned tw2L[100*100];   // tag_attn_w2 bf16 pairs   40.0 KB
  __shared__ unsigned tw1L[TTAG*50];   // tag_w1dt bf16 pairs      12.8 KB
  __shared__ unsigned tagvL[TTAG*50];  // tagv bf16 pairs          12.8 KB
  __shared__ unsigned w1L[CHK*50];     // own w1dt bf16 pairs      12.8 KB
  __shared__ unsigned encL[CHK*100];   // own enc bf16 pairs       25.6 KB
  __shared__ float tavL[100], avL[100], aw3L[500];
  __shared__ float hL[100], cL[100], tcL[100], tsaL[100], nsL[200];
  __shared__ float uL[TTAG], tawL[TTAG];
  __shared__ float ctxL[200], a23L[100], ctxpL[200];
  __shared__ float srowL[CHK], eRL[CHK];
  __shared__ float mwL[GW], SwL[GW], avvL[GW], sclL[GW];
  __shared__ int   aiL[GW];
  __shared__ float zOwnL[16];
  __shared__ float hdrL[4];
  __shared__ float prevL[5];
  __shared__ float MS[2];
  __shared__ int   amiL;

  const int tid = threadIdx.x;
  const int w   = blockIdx.x;
  unsigned long long* REC = (unsigned long long*)(ws + OFF_REC);
  unsigned long long* HC  = (unsigned long long*)(ws + OFF_HC);
  unsigned long long* FLG = (unsigned long long*)(ws + OFF_FLG);

  // ---- hidden-unit ownership: blocks 0..3 -> 4 units, 4..31 -> 3 units ----
  const int nu = (w<4)? 4 : 3;
  const int u0 = (w<4)? w*4 : 16 + (w-4)*3;
  const int nact = nu*4;
  const int jslot = tid>>5, l = tid&31;

  // ---- tiny per-thread weight registers (own gate-rows only) ----
  unsigned wca0=0,wca1=0,wca2=0,wca3=0, wha0=0,wha1=0, wta0=0,wta1=0;
  int row=0;
  if (jslot < nact){
    row = (jslot&3)*100 + u0 + (jslot>>2);
    const float* Wr = dWih + (size_t)row*332;
    wca0=pk2(Wr[2*l],Wr[2*l+1]);
    wca1=pk2(Wr[2*(32+l)],Wr[2*(32+l)+1]);
    wca2=pk2(Wr[2*(64+l)],Wr[2*(64+l)+1]);
    if (l<4) wca3=pk2(Wr[2*(96+l)],Wr[2*(96+l)+1]);
    const float* Wh = dWhh + (size_t)row*100;
    wha0=pk2(Wh[2*l],Wh[2*l+1]);
    if (l<18) wha1=pk2(Wh[2*(32+l)],Wh[2*(32+l)+1]);
    const float* Wt = Wr + 200;
    wta0=pk2(Wt[2*l],Wt[2*l+1]);
    if (l<18) wta1=pk2(Wt[2*(32+l)],Wt[2*(32+l)+1]);
  }
  // ---- LDS preload ----
  for (int i=tid;i<100*100;i+=512){ int k=i/100,p=i%100; aw2L[i]=pk2(aw2 [k*200+2*p], aw2 [k*200+2*p+1]); }
  for (int i=tid;i<100*100;i+=512){ int k=i/100,p=i%100; tw2L[i]=pk2(taw2[k*200+2*p], taw2[k*200+2*p+1]); }
  for (int i=tid;i<TTAG*50;i+=512){ int s=i/50,p=i%50; tw1L[i]=pk2(ws[OFF_TGW1+s*100+2*p], ws[OFF_TGW1+s*100+2*p+1]); }
  for (int i=tid;i<TTAG*50;i+=512){ int s=i/50,p=i%50; tagvL[i]=pk2(ws[OFF_TAGV+s*100+2*p], ws[OFF_TAGV+s*100+2*p+1]); }
  for (int i=tid;i<CHK*50;i+=512){ int r=i/50,p=i%50; w1L[i]=pk2(ws[OFF_W1DT+(w*CHK+r)*100+2*p], ws[OFF_W1DT+(w*CHK+r)*100+2*p+1]); }
  for (int i=tid;i<CHK*100;i+=512){ int r=i/100,p=i%100; encL[i]=pk2(ws[OFF_ENC+(w*CHK+r)*200+2*p], ws[OFF_ENC+(w*CHK+r)*200+2*p+1]); }
  if (tid<100){ tavL[tid]=tav[tid]; avL[tid]=av[tid]; }
  for (int i=tid;i<500;i+=512) aw3L[i]=aw3[i];
  if (tid<5)   prevL[tid]=0.f;
  if (tid<200) ctxL[tid]=ws[OFF_ENC + 2047*200 + tid];   // enc_last for init
  __syncthreads();

  // ---- init: own-row z0 -> h0,c0 -> publish hc buffer 1 + flag=1 ----
  if (jslot < nact){
    float acc=0.f;
    { unsigned u=wca0; acc += ctxL[2*l]*blo(u) + ctxL[2*l+1]*bhi(u); }
    { unsigned u=wca1; acc += ctxL[2*(32+l)]*blo(u) + ctxL[2*(32+l)+1]*bhi(u); }
    { unsigned u=wca2; acc += ctxL[2*(64+l)]*blo(u) + ctxL[2*(64+l)+1]*bhi(u); }
    if (l<4){ unsigned u=wca3; acc += ctxL[2*(96+l)]*blo(u) + ctxL[2*(96+l)+1]*bhi(u); }
    acc += __shfl_xor(acc,1,32); acc += __shfl_xor(acc,2,32);
    acc += __shfl_xor(acc,4,32); acc += __shfl_xor(acc,8,32); acc += __shfl_xor(acc,16,32);
    if (l==0) zOwnL[jslot] = acc + ws[OFF_TGW + 63*400 + row] + ws[OFF_PEW + row];
  }
  __syncthreads();
  if (tid < nu){
    float zi=zOwnL[tid*4+0], zg=zOwnL[tid*4+2], zo=zOwnL[tid*4+3];
    float cc = sigf(zi)*tanhfast(zg);
    float hh = sigf(zo)*tanhfast(cc);
    int u = u0+tid;
    ast64(HC + 128 + u, (unsigned long long)__float_as_uint(hh)
                      | ((unsigned long long)__float_as_uint(cc)<<32));
  }
  vm0();
  if (tid==0) ast64(FLG + (size_t)(64 + GW + w)*16, 1ull);

  for (int t=0; t<TLEN; ++t){
    const unsigned sq = (unsigned)(t+1);
    unsigned long long* slot = REC + (size_t)(t&1)*GW*RECU;
    unsigned long long* hcg  = HC + (size_t)((t+1)&1)*128;
    unsigned long long* hcp  = HC + (size_t)(t&1)*128;
    unsigned long long* fr   = FLG + (size_t)(t&1)*GW*16;
    unsigned long long* fhg  = FLG + (size_t)(64 + ((t+1)&1)*GW)*16;

    // 1: wait hc flags, bulk-read h,c
    { int seen=(tid<GW)?0:1;
      do { if(!seen && (unsigned)ald64(fhg + (size_t)tid*16)==sq) seen=1; }
      while(__syncthreads_count(seen)<512);
    }
    if (tid<100){
      unsigned long long v = ald64(hcg+tid);
      hL[tid]=__uint_as_float((unsigned)v);
      cL[tid]=__uint_as_float((unsigned)(v>>32));
    }
    __syncthreads();
    // 2: tsa[k] = state · tag_attn_w2[k]
    if (tid<400){
      int k=tid>>2, q=tid&3, off=q*50;
      const float* sb = (off<100)? (hL+off) : (cL+(off-100));
      float acc=0.f;
      #pragma unroll
      for (int i=0;i<25;i++){ unsigned u=tw2L[k*100+q*25+i]; acc += sb[2*i]*blo(u) + sb[2*i+1]*bhi(u); }
      acc += __shfl_xor(acc,1,4); acc += __shfl_xor(acc,2,4);
      if (q==0) tsaL[k]=acc;
    }
    __syncthreads();
    { // 3: tag scores (8 thr/tag)
      int sp=tid>>3, l8=tid&7;
      float acc=0.f;
      for (int k=l8;k<100;k+=8){
        unsigned u=tw1L[sp*50+(k>>1)];
        float w1v=(k&1)? bhi(u) : blo(u);
        acc += tanhfast(w1v + tsaL[k]) * tavL[k];
      }
      acc += __shfl_xor(acc,1,8); acc += __shfl_xor(acc,2,8); acc += __shfl_xor(acc,4,8);
      if (l8==0) uL[sp]=acc;
    }
    __syncthreads();
    if (tid<64){ // 4: softmax over 64 tags
      float v=uL[tid], m=v;
      for (int d=1;d<64;d<<=1) m=fmaxf(m,__shfl_xor(m,d,64));
      float e=__expf(v-m), ssum=e;
      for (int d=1;d<64;d<<=1) ssum+=__shfl_xor(ssum,d,64);
      tawL[tid]=e*rcpf(ssum);
    }
    __syncthreads();
    if (tid<400){ // 5: tag_ctx (4 thr/hh) + fold ns
      int hh=tid>>2, q=tid&3;
      float acc=0.f;
      #pragma unroll
      for (int i=0;i<16;i++){
        int s=q*16+i;
        unsigned u=tagvL[s*50+(hh>>1)];
        acc += tawL[s]*((hh&1)? bhi(u):blo(u));
      }
      acc += __shfl_xor(acc,1,4); acc += __shfl_xor(acc,2,4);
      if (q==0){ tcL[hh]=acc; nsL[hh]=hL[hh]+acc; nsL[100+hh]=cL[hh]+acc; }
    }
    __syncthreads();
    if (tid<400){ // 6: a23[k]
      int k=tid>>2, q=tid&3, off=q*50;
      float acc=0.f;
      #pragma unroll
      for (int i=0;i<25;i++){ unsigned u=aw2L[k*100+q*25+i]; acc += nsL[off+2*i]*blo(u) + nsL[off+2*i+1]*bhi(u); }
      acc += __shfl_xor(acc,1,4); acc += __shfl_xor(acc,2,4);
      if (q==0){
        float a3=0.f;
        #pragma unroll
        for (int i=0;i<5;i++) a3 += prevL[i]*aw3L[k*5+i];
        a23L[k]=acc+a3;
      }
    }
    __syncthreads();
    { // 7: own 64 rows' scores (8 lanes/row)
      int r=tid>>3, l8=tid&7;
      float acc=0.f;
      for (int k=l8;k<100;k+=8){
        unsigned u=w1L[r*50+(k>>1)];
        float w1v=(k&1)? bhi(u) : blo(u);
        acc += tanhfast(w1v + a23L[k]) * avL[k];
      }
      acc += __shfl_xor(acc,1,8); acc += __shfl_xor(acc,2,8); acc += __shfl_xor(acc,4,8);
      if (l8==0) srowL[r]=acc;
    }
    __syncthreads();
    if (tid<64){ // 8: local stats + argmax over own 64 rows
      float v=srowL[tid], m=v;
      for (int d=1;d<64;d<<=1) m=fmaxf(m,__shfl_xor(m,d,64));
      float e=__expf(v-m); eRL[tid]=e;
      float Ss=e;
      for (int d=1;d<64;d<<=1) Ss+=__shfl_xor(Ss,d,64);
      float bv=v; int bi=w*CHK+tid;
      for (int d=1;d<64;d<<=1){
        float ov=__shfl_xor(bv,d,64); int oi=__shfl_xor(bi,d,64);
        if (ov>bv || (ov==bv && oi<bi)){ bv=ov; bi=oi; }
      }
      if (tid==0){ hdrL[0]=m; hdrL[1]=Ss; hdrL[2]=bv; ((int*)hdrL)[3]=bi; }
    }
    __syncthreads();
    if (tid<400){ // 9: ctx partial over own rows (2 thr/d)
      int d=tid>>1, hf=tid&1;
      float acc=0.f;
      #pragma unroll 8
      for (int i=0;i<32;i++){
        int rr=hf*32+i;
        unsigned u=encL[rr*100+(d>>1)];
        acc += eRL[rr]*((d&1)? bhi(u):blo(u));
      }
      acc += __shfl_xor(acc,1,2);
      if (hf==0) ctxpL[d]=acc;
    }
    __syncthreads();
    // 10: publish record (plain system stores, 4xbf16/word), then vm0+flag
    {
      unsigned long long* rp = slot + (size_t)w*RECU;
      if (tid<50)
        ast64(rp+tid, (unsigned long long)pk2(ctxpL[4*tid],ctxpL[4*tid+1])
                    | ((unsigned long long)pk2(ctxpL[4*tid+2],ctxpL[4*tid+3])<<32));
      else if (tid>=64 && tid<80){ int j=tid-64;
        ast64(rp+50+j, (unsigned long long)pk2(srowL[4*j],srowL[4*j+1])
                     | ((unsigned long long)pk2(srowL[4*j+2],srowL[4*j+3])<<32)); }
      else if (tid==80)
        ast64(rp+66, (unsigned long long)__float_as_uint(hdrL[0])
                   | ((unsigned long long)__float_as_uint(hdrL[1])<<32));
      else if (tid==81)
        ast64(rp+67, (unsigned long long)__float_as_uint(hdrL[2])
                   | ((unsigned long long)(unsigned)((int*)hdrL)[3]<<32));
    }
    vm0();
    __syncthreads();
    if (tid==0) ast64(fr + (size_t)w*16, (unsigned long long)sq);
    // 11: own-row zpre = PEW[t] + h@Whh + tc@Wiht (overlaps publish propagation)
    if (jslot < nact){
      float acc=0.f;
      { unsigned u=wha0; acc += hL[2*l]*blo(u) + hL[2*l+1]*bhi(u); }
      if (l<18){ unsigned u=wha1; acc += hL[2*(32+l)]*blo(u) + hL[2*(32+l)+1]*bhi(u); }
      { unsigned u=wta0; acc += tcL[2*l]*blo(u) + tcL[2*l+1]*bhi(u); }
      if (l<18){ unsigned u=wta1; acc += tcL[2*(32+l)]*blo(u) + tcL[2*(32+l)+1]*bhi(u); }
      acc += __shfl_xor(acc,1,32); acc += __shfl_xor(acc,2,32);
      acc += __shfl_xor(acc,4,32); acc += __shfl_xor(acc,8,32); acc += __shfl_xor(acc,16,32);
      if (l==0) zOwnL[jslot] = acc + ws[OFF_PEW + t*400 + row];
    }
    // 12: wait all record flags
    { int seen=(tid<GW)?0:1;
      do { if(!seen && (unsigned)ald64(fr + (size_t)tid*16)==sq) seen=1; }
      while(__syncthreads_count(seen)<512);
    }
    // 13: bulk read (no retry): tid<400 ctx words; tid>=448 hdr
    unsigned long long pay[4];
    if (tid<400){
      int dw=tid>>3, s8=tid&7;
      #pragma unroll
      for (int i=0;i<4;i++) pay[i]=ald64(slot + (size_t)(s8*4+i)*RECU + dw);
    } else if (tid>=448){
      int t2=tid-448, r=t2>>1, p=t2&1;
      unsigned long long v = ald64(slot + (size_t)r*RECU + 66 + p);
      if (p==0){ mwL[r]=__uint_as_float((unsigned)v); SwL[r]=__uint_as_float((unsigned)(v>>32)); }
      else     { avvL[r]=__uint_as_float((unsigned)v); aiL[r]=(int)(unsigned)(v>>32); }
    }
    __syncthreads();
    if (tid<GW){ // 14: global stat + argmax reduce (32 lanes)
      float m=mwL[tid];
      for (int d=1;d<32;d<<=1) m=fmaxf(m,__shfl_xor(m,d,32));
      float sc=__expf(mwL[tid]-m); sclL[tid]=sc;
      float Ss=SwL[tid]*sc;
      for (int d=1;d<32;d<<=1) Ss+=__shfl_xor(Ss,d,32);
      float bv=avvL[tid]; int bi=aiL[tid];
      for (int d=1;d<32;d<<=1){
        float ov=__shfl_xor(bv,d,32); int oi=__shfl_xor(bi,d,32);
        if (ov>bv || (ov==bv && oi<bi)){ bv=ov; bi=oi; }
      }
      if (tid==0){ MS[0]=m; MS[1]=Ss; amiL=bi; }
    }
    __syncthreads();
    // 15a: next-step prev window (5 direct reads — data gated by flags already seen)
    if (tid>=440 && tid<445){
      int i=tid-440;
      int st = amiL-1; st = st<0?0:st; st = st>NN-6?NN-6:st;
      int g = st+i, r=g>>6, lr=g&63;
      unsigned long long v = ald64(slot + (size_t)r*RECU + 50 + (lr>>2));
      unsigned half = (lr&2)? (unsigned)(v>>32) : (unsigned)v;
      float sc = (lr&1)? bhi(half) : blo(half);
      prevL[i] = __expf(sc - MS[0]) * rcpf(MS[1]);
    }
    // 15b: ctx assemble (shfl over 8 lanes)
    if (tid<400){
      float rS = rcpf(MS[1]);
      int dw=tid>>3, s8=tid&7;
      float c0=0.f,c1=0.f,c2=0.f,c3=0.f;
      #pragma unroll
      for (int i=0;i<4;i++){
        float sc=sclL[s8*4+i];
        unsigned lo=(unsigned)pay[i], hi=(unsigned)(pay[i]>>32);
        c0 += blo(lo)*sc; c1 += bhi(lo)*sc;
        c2 += blo(hi)*sc; c3 += bhi(hi)*sc;
      }
      #pragma unroll
      for (int d=1;d<8;d<<=1){
        c0 += __shfl_xor(c0,d,8); c1 += __shfl_xor(c1,d,8);
        c2 += __shfl_xor(c2,d,8); c3 += __shfl_xor(c3,d,8);
      }
      if (s8==0){
        ctxL[4*dw+0]=c0*rS; ctxL[4*dw+1]=c1*rS;
        ctxL[4*dw+2]=c2*rS; ctxL[4*dw+3]=c3*rS;
      }
    }
    __syncthreads();
    // 16: own-row z += ctx·Wihc
    if (jslot < nact){
      float acc=0.f;
      { unsigned u=wca0; acc += ctxL[2*l]*blo(u) + ctxL[2*l+1]*bhi(u); }
      { unsigned u=wca1; acc += ctxL[2*(32+l)]*blo(u) + ctxL[2*(32+l)+1]*bhi(u); }
      { unsigned u=wca2; acc += ctxL[2*(64+l)]*blo(u) + ctxL[2*(64+l)+1]*bhi(u); }
      if (l<4){ unsigned u=wca3; acc += ctxL[2*(96+l)]*blo(u) + ctxL[2*(96+l)+1]*bhi(u); }
      acc += __shfl_xor(acc,1,32); acc += __shfl_xor(acc,2,32);
      acc += __shfl_xor(acc,4,32); acc += __shfl_xor(acc,8,32); acc += __shfl_xor(acc,16,32);
      if (l==0) zOwnL[jslot] += acc;
    }
    __syncthreads();
    // 17: own-unit gates; publish h,c + flag for step t+1
    if (tid<nu){
      float zi=zOwnL[tid*4+0], zf=zOwnL[tid*4+1], zg=zOwnL[tid*4+2], zo=zOwnL[tid*4+3];
      int u=u0+tid;
      float cc = sigf(zf)*cL[u] + sigf(zi)*tanhfast(zg);
      float hh = sigf(zo)*tanhfast(cc);
      ast64(hcp+u, (unsigned long long)__float_as_uint(hh)
                 | ((unsigned long long)__float_as_uint(cc)<<32));
      ws[OFF_HOUT + t*100 + u] = hh;
    }
    vm0();
    if (tid==0) ast64(FLG + (size_t)(64 + (t&1)*GW + w)*16, (unsigned long long)(sq+1));
    // next iteration's sticky poll is the inter-step barrier
  }
}

// ---------------- kLoss: parallel logits + log-softmax over V ----------------
__global__ __launch_bounds__(256) void kLoss(const float* outW, const float* outb,
                                             const int* oid, float* ws)
{
  const int b=blockIdx.x, tid=threadIdx.x;
  const int tile=b>>1, hf=b&1, t0=tile*16;
  __shared__ float s_hn[16*100];
  __shared__ int   s_oid[16];
  __shared__ float red[4][16][3];
  for (int i=tid;i<1600;i+=256) s_hn[i]=ws[OFF_HOUT + t0*100 + i];
  if (tid<16) s_oid[tid]=oid[t0+tid];
  __syncthreads();
  const int VSPLIT = 25129;
  int vbeg = hf? VSPLIT : 0;
  int vend = hf? VOC : VSPLIT;
  float rm[16], rs[16], ol[16];
  #pragma unroll
  for (int tt=0;tt<16;tt++){ rm[tt]=-1e30f; rs[tt]=0.f; ol[tt]=-1e30f; }
  for (int v=vbeg+tid; v<vend; v+=256){
    const float4* wr = (const float4*)(outW + (size_t)v*100);
    float acc[16];
    #pragma unroll
    for (int tt=0;tt<16;tt++) acc[tt]=0.f;
    #pragma unroll 5
    for (int q=0;q<25;q++){
      float4 wv = wr[q];
      #pragma unroll
      for (int tt=0;tt<16;tt++){
        float4 hv = *(const float4*)(s_hn + tt*100 + q*4);
        acc[tt] += wv.x*hv.x + wv.y*hv.y + wv.z*hv.z + wv.w*hv.w;
      }
    }
    float bb = outb[v];
    #pragma unroll
    for (int tt=0;tt<16;tt++){
      float lg = acc[tt] + bb;
      if (v == s_oid[tt]) ol[tt] = fmaxf(ol[tt], lg);
      if (lg <= rm[tt]) rs[tt] += __expf(lg - rm[tt]);
      else { rs[tt] = rs[tt]*__expf(rm[tt]-lg) + 1.0f; rm[tt]=lg; }
    }
  }
  int wv2=tid>>6, ln=tid&63;
  #pragma unroll
  for (int tt=0;tt<16;tt++){
    float m=rm[tt], sv=rs[tt], o=ol[tt];
    for (int d=1;d<64;d<<=1){
      float om=__shfl_xor(m,d,64), os=__shfl_xor(sv,d,64), oo=__shfl_xor(o,d,64);
      float M2=fmaxf(m,om);
      sv = sv*__expf(m-M2) + os*__expf(om-M2);
      m=M2; o=fmaxf(o,oo);
    }
    if (ln==0){ red[wv2][tt][0]=m; red[wv2][tt][1]=sv; red[wv2][tt][2]=o; }
  }
  __syncthreads();
  if (tid<16){
    float M=-1e30f;
    for (int q=0;q<4;q++) M=fmaxf(M,red[q][tid][0]);
    float S=0.f, O=-1e30f;
    for (int q=0;q<4;q++){ S += red[q][tid][1]*__expf(red[q][tid][0]-M); O=fmaxf(O,red[q][tid][2]); }
    float* pb = ws + OFF_PB + (((tile*2)+hf)*16 + tid)*4;
    pb[0]=M; pb[1]=S; pb[2]=O;
  }
}

// ---------------- kFinal: combine halves, sum, scale ----------------
__global__ void kFinal(const float* weight, float* ws, float* out){
  __shared__ float red[256];
  int tid=threadIdx.x;
  float acc=0.f;
  for (int t=tid;t<TLEN;t+=256){
    int tile=t>>4, tt=t&15;
    const float* p0 = ws + OFF_PB + ((tile*2+0)*16+tt)*4;
    const float* p1 = ws + OFF_PB + ((tile*2+1)*16+tt)*4;
    float M=fmaxf(p0[0],p1[0]);
    float S=p0[1]*__expf(p0[0]-M) + p1[1]*__expf(p1[0]-M);
    float O=fmaxf(p0[2],p1[2]);
    acc += (M + logf(S)) - O;
  }
  red[tid]=acc; __syncthreads();
  for (int d=128; d>0; d>>=1){
    if (tid<d) red[tid]+=red[tid+d];
    __syncthreads();
  }
  if (tid==0) out[0]=red[0]*weight[0];
}

// ---------------- launch ----------------
extern "C" void kernel_launch(void* const* d_in, const int* in_sizes, int n_in,
                              void* d_out, int out_size, void* d_ws, size_t ws_size,
                              hipStream_t stream) {
  const int*   src      = (const int*)  d_in[0];
  const int*   tag      = (const int*)  d_in[1];
  const int*   oid      = (const int*)  d_in[2];
  const float* weight   = (const float*)d_in[3];
  const float* emb_char = (const float*)d_in[4];
  const float* emb_tag  = (const float*)d_in[5];
  const float* fWih=(const float*)d_in[6],  *fWhh=(const float*)d_in[7],  *fb=(const float*)d_in[8];
  const float* bWih=(const float*)d_in[9],  *bWhh=(const float*)d_in[10], *bb=(const float*)d_in[11];
  const float* tWih=(const float*)d_in[12], *tWhh=(const float*)d_in[13], *tb=(const float*)d_in[14];
  const float* dWih=(const float*)d_in[15], *dWhh=(const float*)d_in[16], *db=(const float*)d_in[17];
  const float* aw1 =(const float*)d_in[18], *aw2=(const float*)d_in[19];
  const float* aw3 =(const float*)d_in[20], *av =(const float*)d_in[21];
  const float* taw1=(const float*)d_in[22], *taw2=(const float*)d_in[23], *tavv=(const float*)d_in[24];
  const float* outW=(const float*)d_in[25], *outb=(const float*)d_in[26];
  float* ws  = (float*)d_ws;
  float* out = (float*)d_out;

  kInit<<<8, 256, 0, stream>>>(ws);
  kPrep<<<2*NN+TTAG+TLEN, 512, 0, stream>>>(src,tag,oid,emb_char,emb_tag,
                                            fWih,fb,bWih,bb,tWih,tb,dWih,db,ws);
  kEnc<<<3,512,0,stream>>>(fWhh,bWhh,tWhh,taw1,dWih,ws);
  kMid<<<NN,128,0,stream>>>(aw1,ws);
  kDec<<<GW,512,0,stream>>>(dWhh,dWih,aw2,aw3,av,taw2,tavv,ws);
  kLoss<<<256,256,0,stream>>>(outW,outb,oid,ws);
  kFinal<<<1,256,0,stream>>>(weight,ws,out);
}

// Round 9
// 34195.740 us; speedup vs baseline: 10.9942x; 1.0561x over previous
//
#include <hip/hip_runtime.h>
#include <math.h>

// ---------------- problem sizes ----------------
#define NN   2048   // source length
#define TLEN 2048   // target length
#define TTAG 64     // tags
#define VOC  50257
#define GW   32     // decoder blocks; each owns CHK source rows + 3-4 hidden units
#define CHK  64     // source rows per block
#define RECU 80     // u64 stride per record (68 used)
static_assert(GW * CHK == NN, "chunking");

// ---------------- workspace layout (float units) ----------------
#define OFF_XF    0                          // NN*400
#define OFF_XB    (OFF_XF  + NN*400)         // NN*400
#define OFF_TGX   (OFF_XB  + NN*400)         // TTAG*400
#define OFF_PEW   (OFF_TGX + TTAG*400)       // TLEN*400
#define OFF_ENC   (OFF_PEW + TLEN*400)       // NN*200
#define OFF_W1DT  (OFF_ENC + NN*200)         // NN*100
#define OFF_TAGV  (OFF_W1DT+ NN*100)         // TTAG*100
#define OFF_TGW1  (OFF_TAGV+ TTAG*100)       // TTAG*100
#define OFF_TGW   (OFF_TGW1+ TTAG*100)       // TTAG*400
#define OFF_HOUT  (OFF_TGW + TTAG*400)       // TLEN*100
#define OFF_REC   (OFF_HOUT+ TLEN*100)       // 2*GW*RECU u64
#define OFF_HC    (OFF_REC + 2*GW*RECU*2)    // 2*128 u64
#define OFF_FLG   (OFF_HC  + 2*128*2)        // 2048 u64 flags (128B-spread)
#define OFF_PB    (OFF_FLG + 4096)           // loss partials

// record u64 words: [0..49] ctxp 4xbf16/word, [50..65] scores 4xbf16/word (64 rows),
//   [66]={m f32 | S f32}, [67]={amax f32 | idx}
// hc buffer b: word u = {h[u] f32 | c[u] f32}
// Protocol: data stores (system write-through) -> wave-local s_waitcnt vmcnt(0) ->
// one flag store by same wave. Consumer: ONE wave spins on flags via __all
// (no block barrier per poll round) -> single release barrier -> bulk read.

// ---------------- helpers ----------------
__device__ __forceinline__ float rcpf(float x){ return __builtin_amdgcn_rcpf(x); }
__device__ __forceinline__ float sigf(float x){ return rcpf(1.0f+__expf(-x)); }
__device__ __forceinline__ float tanhfast(float x){
  float e = __expf(2.0f*x);
  return 1.0f - 2.0f*rcpf(e+1.0f);
}
__device__ __forceinline__ unsigned short f2b(float x){
  unsigned b=__float_as_uint(x);
  return (unsigned short)((b + 0x7fffu + ((b>>16)&1u))>>16);
}
__device__ __forceinline__ unsigned pk2(float a,float b){ return (unsigned)f2b(a) | ((unsigned)f2b(b)<<16); }
__device__ __forceinline__ float blo(unsigned u){ return __uint_as_float(u<<16); }
__device__ __forceinline__ float bhi(unsigned u){ return __uint_as_float(u&0xffff0000u); }

__device__ __forceinline__ unsigned long long ald64(const unsigned long long* p){
  return __hip_atomic_load(p,__ATOMIC_RELAXED,__HIP_MEMORY_SCOPE_SYSTEM);
}
__device__ __forceinline__ void ast64(unsigned long long* p, unsigned long long v){
  __hip_atomic_store(p,v,__ATOMIC_RELAXED,__HIP_MEMORY_SCOPE_SYSTEM);
}
__device__ __forceinline__ void vm0(){ asm volatile("s_waitcnt vmcnt(0)" ::: "memory"); }

// ---------------- kInit: zero flag region (every launch / replay) ----------------
__global__ void kInit(float* ws){
  unsigned long long* f = (unsigned long long*)(ws + OFF_FLG);
  int i = blockIdx.x*256 + threadIdx.x;
  if (i < 2048) ast64(f+i, 0ull);
}

// ---------------- kPrep: all input-side GEMVs (parallel) ----------------
__global__ __launch_bounds__(512) void kPrep(
    const int* src, const int* tag, const int* oid,
    const float* emb_char, const float* emb_tag,
    const float* fWih, const float* fb,
    const float* bWih, const float* bb,
    const float* tWih, const float* tb,
    const float* dWih, const float* db, float* ws)
{
  int r = blockIdx.x, j = threadIdx.x;
  if (j >= 400) return;
  if (r < NN) {
    const float* e = emb_char + (size_t)src[r]*32;
    const float* Wr = fWih + j*32;
    float a = fb[j];
    #pragma unroll
    for (int q=0;q<32;q++) a += e[q]*Wr[q];
    ws[OFF_XF + r*400 + j] = a;
  } else if (r < 2*NN) {
    int n = r - NN;
    const float* e = emb_char + (size_t)src[n]*32;
    const float* Wr = bWih + j*32;
    float a = bb[j];
    #pragma unroll
    for (int q=0;q<32;q++) a += e[q]*Wr[q];
    ws[OFF_XB + n*400 + j] = a;
  } else if (r < 2*NN + TTAG) {
    int s = r - 2*NN;
    const float* e = emb_tag + (size_t)tag[s]*32;
    const float* Wr = tWih + j*32;
    float a = tb[j];
    #pragma unroll
    for (int q=0;q<32;q++) a += e[q]*Wr[q];
    ws[OFF_TGX + s*400 + j] = a;
  } else {
    int t = r - (2*NN + TTAG);
    int pid = (t==0) ? 0 : oid[t-1];
    const float* e = emb_char + (size_t)pid*32;
    const float* Wr = dWih + (size_t)j*332 + 300;
    float a = db[j];
    #pragma unroll
    for (int q=0;q<32;q++) a += e[q]*Wr[q];
    ws[OFF_PEW + t*400 + j] = a;
  }
}

// ---------------- kEnc: sequential LSTM scans (3 independent blocks) ----------------
struct EncShared {
  float tvs[TTAG*100];
  float sa [TTAG*64];
  float hbuf[100];
  float zbuf[400];
};

__device__ void lstm_block(const float* Whh, const float* xbase, float* ws,
                           int reverse, int col, EncShared* sh)
{
  int tid = threadIdx.x;
  float whh[100];
  if (tid < 400){
    #pragma unroll
    for (int k=0;k<100;k++) whh[k] = Whh[tid*100+k];
  }
  float c = 0.f;
  if (tid < 100) sh->hbuf[tid] = 0.f;
  __syncthreads();
  for (int i=0;i<NN;i++){
    int n = reverse ? (NN-1-i) : i;
    if (tid < 400){
      float z = xbase[n*400+tid];
      #pragma unroll 10
      for (int k=0;k<100;k++) z += whh[k]*sh->hbuf[k];
      sh->zbuf[tid] = z;
    }
    __syncthreads();
    if (tid < 100){
      float zi=sh->zbuf[tid], zf=sh->zbuf[tid+100], zg=sh->zbuf[tid+200], zo=sh->zbuf[tid+300];
      c = sigf(zf)*c + sigf(zi)*tanhfast(zg);
      float h = sigf(zo)*tanhfast(c);
      sh->hbuf[tid] = h;
      ws[OFF_ENC + n*200 + col + tid] = h;
    }
    __syncthreads();
  }
}

__global__ __launch_bounds__(512,1) void kEnc(
    const float* fWhh, const float* bWhh, const float* tWhh,
    const float* taw1, const float* dWih, float* ws)
{
  __shared__ EncShared sh;
  int b = blockIdx.x, tid = threadIdx.x;
  if (b == 0){ lstm_block(fWhh, ws+OFF_XF, ws, 0, 0,   &sh); return; }
  if (b == 1){ lstm_block(bWhh, ws+OFF_XB, ws, 1, 100, &sh); return; }

  // ---- block 2: tag LSTM + self-attn + tagv-derived tables ----
  {
    float whh[100];
    if (tid<400){
      #pragma unroll
      for (int k=0;k<100;k++) whh[k] = tWhh[tid*100+k];
    }
    float c = 0.f;
    if (tid<100) sh.hbuf[tid] = 0.f;
    __syncthreads();
    for (int s=0;s<TTAG;s++){
      if (tid<400){
        float z = ws[OFF_TGX + s*400 + tid];
        #pragma unroll 10
        for (int k=0;k<100;k++) z += whh[k]*sh.hbuf[k];
        sh.zbuf[tid] = z;
      }
      __syncthreads();
      if (tid<100){
        float zi=sh.zbuf[tid], zf=sh.zbuf[tid+100], zg=sh.zbuf[tid+200], zo=sh.zbuf[tid+300];
        c = sigf(zf)*c + sigf(zi)*tanhfast(zg);
        float h = sigf(zo)*tanhfast(c);
        sh.hbuf[tid] = h;
        sh.tvs[s*100+tid] = h;
      }
      __syncthreads();
    }
  }
  for (int idx=tid; idx<TTAG*TTAG; idx+=512){
    int s=idx>>6, t2=idx&63;
    float a=0.f;
    #pragma unroll 10
    for (int h=0;h<100;h++) a += sh.tvs[s*100+h]*sh.tvs[t2*100+h];
    sh.sa[idx]=a;
  }
  __syncthreads();
  if (tid<TTAG){
    float m=-1e30f;
    for (int t2=0;t2<64;t2++) m = fmaxf(m, sh.sa[tid*64+t2]);
    float sum=0.f;
    for (int t2=0;t2<64;t2++){ float e=__expf(sh.sa[tid*64+t2]-m); sh.sa[tid*64+t2]=e; sum+=e; }
    float r=1.f/sum;
    for (int t2=0;t2<64;t2++) sh.sa[tid*64+t2]*=r;
  }
  __syncthreads();
  float tvloc[13]; int cnt=0;
  for (int idx=tid; idx<TTAG*100; idx+=512){
    int t2=idx/100, hh=idx%100;
    float a = sh.tvs[t2*100+hh];
    for (int s=0;s<64;s++) a += sh.tvs[s*100+hh]*sh.sa[s*64+t2];
    tvloc[cnt++]=a;
    ws[OFF_TAGV+idx]=a;
  }
  __syncthreads();
  float* tagvs = sh.sa;
  cnt=0;
  for (int idx=tid; idx<TTAG*100; idx+=512) tagvs[idx]=tvloc[cnt++];
  __syncthreads();
  for (int idx=tid; idx<TTAG*100; idx+=512){
    int s=idx/100, k=idx%100;
    float a=0.f;
    #pragma unroll 10
    for (int h=0;h<100;h++) a += tagvs[s*100+h]*taw1[k*100+h];
    ws[OFF_TGW1+idx]=a;
  }
  for (int idx=tid; idx<TTAG*400; idx+=512){
    int s=idx/400, j=idx%400;
    const float* Wr = dWih + (size_t)j*332 + 200;
    float a=0.f;
    #pragma unroll 10
    for (int h=0;h<100;h++) a += tagvs[s*100+h]*Wr[h];
    ws[OFF_TGW+idx]=a;
  }
}

// ---------------- kMid: w1dt = enc @ attn_w1.T ----------------
__global__ void kMid(const float* aw1, float* ws){
  __shared__ float er[200];
  int n=blockIdx.x, tid=threadIdx.x;
  for (int i=tid;i<200;i+=128) er[i]=ws[OFF_ENC+n*200+i];
  __syncthreads();
  if (tid<100){
    const float* Wr = aw1 + tid*200;
    float a=0.f;
    #pragma unroll 8
    for (int d=0;d<200;d++) a += er[d]*Wr[d];
    ws[OFF_W1DT + n*100 + tid]=a;
  }
}

// ---------------- kDec: de-replicated decoder, wave-local sync machinery ----------------
__global__ __launch_bounds__(512) void kDec(
    const float* dWhh, const float* dWih,
    const float* aw2, const float* aw3, const float* av,
    const float* taw2, const float* tav, float* ws)
{
  // padded strides: 101 per 100-wide row, 51 per 50-wide row (bank-conflict fix)
  __shared__ unsigned aw2L[100*101];
  __shared__ unsigned tw2L[100*101];
  __shared__ unsigned tw1L[TTAG*51];
  __shared__ unsigned tagvL[TTAG*51];
  __shared__ unsigned w1L[CHK*51];
  __shared__ unsigned encL[CHK*101];
  __shared__ float tavL[100], avL[100], aw3L[500];
  __shared__ float hL[100], cL[100], tcL[100], tsaL[100], nsL[200];
  __shared__ float uL[TTAG], tawL[TTAG];
  __shared__ float ctxL[200], a23L[100], ctxpL[200];
  __shared__ float srowL[CHK], eRL[CHK];
  __shared__ float sclL[GW];
  __shared__ float zOwnL[16];
  __shared__ float hdrL[4];
  __shared__ float prevL[5];
  __shared__ float MS[2];
  __shared__ int   amiL;

  const int tid = threadIdx.x;
  const int w   = blockIdx.x;
  unsigned long long* REC = (unsigned long long*)(ws + OFF_REC);
  unsigned long long* HC  = (unsigned long long*)(ws + OFF_HC);
  unsigned long long* FLG = (unsigned long long*)(ws + OFF_FLG);

  // ---- hidden-unit ownership: blocks 0..3 -> 4 units, 4..31 -> 3 units ----
  const int nu = (w<4)? 4 : 3;
  const int u0 = (w<4)? w*4 : 16 + (w-4)*3;
  const int nact = nu*4;
  const int jslot = tid>>5, l = tid&31;

  // ---- tiny per-thread weight registers (own gate-rows only) ----
  unsigned wca0=0,wca1=0,wca2=0,wca3=0, wha0=0,wha1=0, wta0=0,wta1=0;
  int row=0;
  if (jslot < nact){
    row = (jslot&3)*100 + u0 + (jslot>>2);
    const float* Wr = dWih + (size_t)row*332;
    wca0=pk2(Wr[2*l],Wr[2*l+1]);
    wca1=pk2(Wr[2*(32+l)],Wr[2*(32+l)+1]);
    wca2=pk2(Wr[2*(64+l)],Wr[2*(64+l)+1]);
    if (l<4) wca3=pk2(Wr[2*(96+l)],Wr[2*(96+l)+1]);
    const float* Wh = dWhh + (size_t)row*100;
    wha0=pk2(Wh[2*l],Wh[2*l+1]);
    if (l<18) wha1=pk2(Wh[2*(32+l)],Wh[2*(32+l)+1]);
    const float* Wt = Wr + 200;
    wta0=pk2(Wt[2*l],Wt[2*l+1]);
    if (l<18) wta1=pk2(Wt[2*(32+l)],Wt[2*(32+l)+1]);
  }
  // ---- LDS preload (padded strides) ----
  for (int i=tid;i<100*100;i+=512){ int k=i/100,p=i%100; aw2L[k*101+p]=pk2(aw2 [k*200+2*p], aw2 [k*200+2*p+1]); }
  for (int i=tid;i<100*100;i+=512){ int k=i/100,p=i%100; tw2L[k*101+p]=pk2(taw2[k*200+2*p], taw2[k*200+2*p+1]); }
  for (int i=tid;i<TTAG*50;i+=512){ int s=i/50,p=i%50; tw1L[s*51+p]=pk2(ws[OFF_TGW1+s*100+2*p], ws[OFF_TGW1+s*100+2*p+1]); }
  for (int i=tid;i<TTAG*50;i+=512){ int s=i/50,p=i%50; tagvL[s*51+p]=pk2(ws[OFF_TAGV+s*100+2*p], ws[OFF_TAGV+s*100+2*p+1]); }
  for (int i=tid;i<CHK*50;i+=512){ int r=i/50,p=i%50; w1L[r*51+p]=pk2(ws[OFF_W1DT+(w*CHK+r)*100+2*p], ws[OFF_W1DT+(w*CHK+r)*100+2*p+1]); }
  for (int i=tid;i<CHK*100;i+=512){ int r=i/100,p=i%100; encL[r*101+p]=pk2(ws[OFF_ENC+(w*CHK+r)*200+2*p], ws[OFF_ENC+(w*CHK+r)*200+2*p+1]); }
  if (tid<100){ tavL[tid]=tav[tid]; avL[tid]=av[tid]; }
  for (int i=tid;i<500;i+=512) aw3L[i]=aw3[i];
  if (tid<5)   prevL[tid]=0.f;
  if (tid<200) ctxL[tid]=ws[OFF_ENC + 2047*200 + tid];   // enc_last for init
  __syncthreads();

  // ---- init: own-row z0 -> h0,c0 -> publish hc buffer 1 + flag=1 (wave-local) ----
  if (jslot < nact){
    float acc=0.f;
    { unsigned u=wca0; acc += ctxL[2*l]*blo(u) + ctxL[2*l+1]*bhi(u); }
    { unsigned u=wca1; acc += ctxL[2*(32+l)]*blo(u) + ctxL[2*(32+l)+1]*bhi(u); }
    { unsigned u=wca2; acc += ctxL[2*(64+l)]*blo(u) + ctxL[2*(64+l)+1]*bhi(u); }
    if (l<4){ unsigned u=wca3; acc += ctxL[2*(96+l)]*blo(u) + ctxL[2*(96+l)+1]*bhi(u); }
    acc += __shfl_xor(acc,1,32); acc += __shfl_xor(acc,2,32);
    acc += __shfl_xor(acc,4,32); acc += __shfl_xor(acc,8,32); acc += __shfl_xor(acc,16,32);
    if (l==0) zOwnL[jslot] = acc + ws[OFF_TGW + 63*400 + row] + ws[OFF_PEW + row];
  }
  __syncthreads();
  if (tid < 64){
    if (tid < nu){
      float zi=zOwnL[tid*4+0], zg=zOwnL[tid*4+2], zo=zOwnL[tid*4+3];
      float cc = sigf(zi)*tanhfast(zg);
      float hh = sigf(zo)*tanhfast(cc);
      int u = u0+tid;
      ast64(HC + 128 + u, (unsigned long long)__float_as_uint(hh)
                        | ((unsigned long long)__float_as_uint(cc)<<32));
    }
    vm0();
    if (tid==0) ast64(FLG + (size_t)(64 + GW + w)*16, 1ull);
  }

  for (int t=0; t<TLEN; ++t){
    const unsigned sq = (unsigned)(t+1);
    unsigned long long* slot = REC + (size_t)(t&1)*GW*RECU;
    unsigned long long* hcg  = HC + (size_t)((t+1)&1)*128;
    unsigned long long* hcp  = HC + (size_t)(t&1)*128;
    unsigned long long* fr   = FLG + (size_t)(t&1)*GW*16;
    unsigned long long* fhg  = FLG + (size_t)(64 + ((t+1)&1)*GW)*16;

    // PH1: wave 0 polls hc flags (__all) + reads h,c into LDS; single release barrier
    if (tid < 64){
      int ok = (tid >= GW) ? 1 : 0;
      for(;;){
        if (!ok) ok = ((unsigned)ald64(fhg + (size_t)tid*16) == sq);
        if (__all(ok)) break;
      }
      if (tid < 50){
        unsigned long long v0 = ald64(hcg + 2*tid), v1 = ald64(hcg + 2*tid + 1);
        hL[2*tid]   = __uint_as_float((unsigned)v0); cL[2*tid]   = __uint_as_float((unsigned)(v0>>32));
        hL[2*tid+1] = __uint_as_float((unsigned)v1); cL[2*tid+1] = __uint_as_float((unsigned)(v1>>32));
      }
    }
    __syncthreads();                                      // B1
    // PH2: tsa[k] = state · tag_attn_w2[k]
    if (tid<400){
      int k=tid>>2, q=tid&3, off=q*50;
      const float* sb = (off<100)? (hL+off) : (cL+(off-100));
      float acc=0.f;
      #pragma unroll
      for (int i=0;i<25;i++){ unsigned u=tw2L[k*101+q*25+i]; acc += sb[2*i]*blo(u) + sb[2*i+1]*bhi(u); }
      acc += __shfl_xor(acc,1,4); acc += __shfl_xor(acc,2,4);
      if (q==0) tsaL[k]=acc;
    }
    __syncthreads();                                      // B2
    { // PH3: tag scores (8 thr/tag)
      int sp=tid>>3, l8=tid&7;
      float acc=0.f;
      for (int k=l8;k<100;k+=8){
        unsigned u=tw1L[sp*51+(k>>1)];
        float w1v=(k&1)? bhi(u) : blo(u);
        acc += tanhfast(w1v + tsaL[k]) * tavL[k];
      }
      acc += __shfl_xor(acc,1,8); acc += __shfl_xor(acc,2,8); acc += __shfl_xor(acc,4,8);
      if (l8==0) uL[sp]=acc;
    }
    __syncthreads();                                      // B3
    if (tid<64){ // PH4: softmax over 64 tags
      float v=uL[tid], m=v;
      for (int d=1;d<64;d<<=1) m=fmaxf(m,__shfl_xor(m,d,64));
      float e=__expf(v-m), ssum=e;
      for (int d=1;d<64;d<<=1) ssum+=__shfl_xor(ssum,d,64);
      tawL[tid]=e*rcpf(ssum);
    }
    __syncthreads();                                      // B4
    if (tid<400){ // PH5: tag_ctx (4 thr/hh) + fold ns
      int hh=tid>>2, q=tid&3;
      float acc=0.f;
      #pragma unroll
      for (int i=0;i<16;i++){
        int s=q*16+i;
        unsigned u=tagvL[s*51+(hh>>1)];
        acc += tawL[s]*((hh&1)? bhi(u):blo(u));
      }
      acc += __shfl_xor(acc,1,4); acc += __shfl_xor(acc,2,4);
      if (q==0){ tcL[hh]=acc; nsL[hh]=hL[hh]+acc; nsL[100+hh]=cL[hh]+acc; }
    }
    __syncthreads();                                      // B5
    if (tid<400){ // PH6: a23[k]
      int k=tid>>2, q=tid&3, off=q*50;
      float acc=0.f;
      #pragma unroll
      for (int i=0;i<25;i++){ unsigned u=aw2L[k*101+q*25+i]; acc += nsL[off+2*i]*blo(u) + nsL[off+2*i+1]*bhi(u); }
      acc += __shfl_xor(acc,1,4); acc += __shfl_xor(acc,2,4);
      if (q==0){
        float a3=0.f;
        #pragma unroll
        for (int i=0;i<5;i++) a3 += prevL[i]*aw3L[k*5+i];
        a23L[k]=acc+a3;
      }
    }
    __syncthreads();                                      // B6
    { // PH7: own 64 rows' scores (8 lanes/row)
      int r=tid>>3, l8=tid&7;
      float acc=0.f;
      for (int k=l8;k<100;k+=8){
        unsigned u=w1L[r*51+(k>>1)];
        float w1v=(k&1)? bhi(u) : blo(u);
        acc += tanhfast(w1v + a23L[k]) * avL[k];
      }
      acc += __shfl_xor(acc,1,8); acc += __shfl_xor(acc,2,8); acc += __shfl_xor(acc,4,8);
      if (l8==0) srowL[r]=acc;
    }
    __syncthreads();                                      // B7
    if (tid<64){ // PH8: local stats + argmax over own 64 rows
      float v=srowL[tid], m=v;
      for (int d=1;d<64;d<<=1) m=fmaxf(m,__shfl_xor(m,d,64));
      float e=__expf(v-m); eRL[tid]=e;
      float Ss=e;
      for (int d=1;d<64;d<<=1) Ss+=__shfl_xor(Ss,d,64);
      float bv=v; int bi=w*CHK+tid;
      for (int d=1;d<64;d<<=1){
        float ov=__shfl_xor(bv,d,64); int oi=__shfl_xor(bi,d,64);
        if (ov>bv || (ov==bv && oi<bi)){ bv=ov; bi=oi; }
      }
      if (tid==0){ hdrL[0]=m; hdrL[1]=Ss; hdrL[2]=bv; ((int*)hdrL)[3]=bi; }
    }
    __syncthreads();                                      // B8
    if (tid<400){ // PH9: ctx partial over own rows (2 thr/d)
      int d=tid>>1, hf=tid&1;
      float acc=0.f;
      #pragma unroll 8
      for (int i=0;i<32;i++){
        int rr=hf*32+i;
        unsigned u=encL[rr*101+(d>>1)];
        acc += eRL[rr]*((d&1)? bhi(u):blo(u));
      }
      acc += __shfl_xor(acc,1,2);
      if (hf==0) ctxpL[d]=acc;
    }
    __syncthreads();                                      // B9

    // PH10/11: wave 7 publishes record (wave-local vm0+flag) then its zpre;
    //          waves 0-6 do their zpre rows.
    #define ZPRE_ROW() do{ \
      if (jslot < nact){ \
        float acc=0.f; \
        { unsigned u=wha0; acc += hL[2*l]*blo(u) + hL[2*l+1]*bhi(u); } \
        if (l<18){ unsigned u=wha1; acc += hL[2*(32+l)]*blo(u) + hL[2*(32+l)+1]*bhi(u); } \
        { unsigned u=wta0; acc += tcL[2*l]*blo(u) + tcL[2*l+1]*bhi(u); } \
        if (l<18){ unsigned u=wta1; acc += tcL[2*(32+l)]*blo(u) + tcL[2*(32+l)+1]*bhi(u); } \
        acc += __shfl_xor(acc,1,32); acc += __shfl_xor(acc,2,32); \
        acc += __shfl_xor(acc,4,32); acc += __shfl_xor(acc,8,32); acc += __shfl_xor(acc,16,32); \
        if (l==0) zOwnL[jslot] = acc + ws[OFF_PEW + t*400 + row]; \
      } \
    }while(0)

    if (tid < 448){
      ZPRE_ROW();
    } else {
      int lane = tid-448;
      unsigned long long* rp = slot + (size_t)w*RECU;
      if (lane < 50)
        ast64(rp+lane, (unsigned long long)pk2(ctxpL[4*lane],ctxpL[4*lane+1])
                     | ((unsigned long long)pk2(ctxpL[4*lane+2],ctxpL[4*lane+3])<<32));
      else { int j=lane-50;  // j=0..13 -> words 50..63
        ast64(rp+lane, (unsigned long long)pk2(srowL[4*j],srowL[4*j+1])
                     | ((unsigned long long)pk2(srowL[4*j+2],srowL[4*j+3])<<32)); }
      if (lane < 2){ int j=14+lane;  // words 64,65
        ast64(rp+64+lane, (unsigned long long)pk2(srowL[4*j],srowL[4*j+1])
                        | ((unsigned long long)pk2(srowL[4*j+2],srowL[4*j+3])<<32)); }
      else if (lane==2)
        ast64(rp+66, (unsigned long long)__float_as_uint(hdrL[0])
                   | ((unsigned long long)__float_as_uint(hdrL[1])<<32));
      else if (lane==3)
        ast64(rp+67, (unsigned long long)__float_as_uint(hdrL[2])
                   | ((unsigned long long)(unsigned)((int*)hdrL)[3]<<32));
      vm0();
      if (lane==0) ast64(fr + (size_t)w*16, (unsigned long long)sq);
      ZPRE_ROW();   // jslot 14,15 (active only for blocks 0-3)
    }

    // PH12: wave 0 polls record flags (__all); single release barrier
    if (tid < 64){
      int ok = (tid >= GW) ? 1 : 0;
      for(;;){
        if (!ok) ok = ((unsigned)ald64(fr + (size_t)tid*16) == sq);
        if (__all(ok)) break;
      }
    }
    __syncthreads();                                      // B10
    // PH13: waves 0-6 bulk-read ctx words; wave 7 reads hdrs + in-wave reduce
    unsigned long long pay[4];
    if (tid<400){
      int dw=tid>>3, s8=tid&7;
      #pragma unroll
      for (int i=0;i<4;i++) pay[i]=ald64(slot + (size_t)(s8*4+i)*RECU + dw);
    } else if (tid>=448){
      int lane=tid-448, r=lane&31, up=lane>>5;
      unsigned long long v = ald64(slot + (size_t)r*RECU + 66 + up);
      float x0 = __uint_as_float((unsigned)v);            // m (lo) or av (hi half's lo)
      float x1 = __uint_as_float((unsigned)(v>>32));      // S or ai-bits
      int   xi = (int)(unsigned)(v>>32);
      float pv = x0; int pi = xi;
      #pragma unroll
      for (int d=1;d<32;d<<=1){
        float ov=__shfl_xor(pv,d,32); int oi=__shfl_xor(pi,d,32);
        if (up){ if (ov>pv || (ov==pv && oi<pi)){ pv=ov; pi=oi; } }
        else   { pv = fmaxf(pv,ov); }
      }
      if (!up){
        float sc = __expf(x0 - pv);                       // pv = M
        sclL[r] = sc;
        float ss = sc * x1;
        #pragma unroll
        for (int d=1;d<32;d<<=1) ss += __shfl_xor(ss,d,32);
        if (r==0){ MS[0]=pv; MS[1]=ss; }
      } else {
        if (r==0) amiL = pi;
      }
    }
    __syncthreads();                                      // B11
    // PH15a: next-step prev window (5 direct reads; flag-gated data)
    if (tid>=440 && tid<445){
      int i=tid-440;
      int st = amiL-1; st = st<0?0:st; st = st>NN-6?NN-6:st;
      int g = st+i, r=g>>6, lr=g&63;
      unsigned long long v = ald64(slot + (size_t)r*RECU + 50 + (lr>>2));
      unsigned half = (lr&2)? (unsigned)(v>>32) : (unsigned)v;
      float sc = (lr&1)? bhi(half) : blo(half);
      prevL[i] = __expf(sc - MS[0]) * rcpf(MS[1]);
    }
    // PH15b: ctx assemble (shfl over 8 lanes)
    if (tid<400){
      float rS = rcpf(MS[1]);
      int dw=tid>>3, s8=tid&7;
      float c0=0.f,c1=0.f,c2=0.f,c3=0.f;
      #pragma unroll
      for (int i=0;i<4;i++){
        float sc=sclL[s8*4+i];
        unsigned lo=(unsigned)pay[i], hi=(unsigned)(pay[i]>>32);
        c0 += blo(lo)*sc; c1 += bhi(lo)*sc;
        c2 += blo(hi)*sc; c3 += bhi(hi)*sc;
      }
      #pragma unroll
      for (int d=1;d<8;d<<=1){
        c0 += __shfl_xor(c0,d,8); c1 += __shfl_xor(c1,d,8);
        c2 += __shfl_xor(c2,d,8); c3 += __shfl_xor(c3,d,8);
      }
      if (s8==0){
        ctxL[4*dw+0]=c0*rS; ctxL[4*dw+1]=c1*rS;
        ctxL[4*dw+2]=c2*rS; ctxL[4*dw+3]=c3*rS;
      }
    }
    __syncthreads();                                      // B12
    // PH16: own-row z += ctx·Wihc
    if (jslot < nact){
      float acc=0.f;
      { unsigned u=wca0; acc += ctxL[2*l]*blo(u) + ctxL[2*l+1]*bhi(u); }
      { unsigned u=wca1; acc += ctxL[2*(32+l)]*blo(u) + ctxL[2*(32+l)+1]*bhi(u); }
      { unsigned u=wca2; acc += ctxL[2*(64+l)]*blo(u) + ctxL[2*(64+l)+1]*bhi(u); }
      if (l<4){ unsigned u=wca3; acc += ctxL[2*(96+l)]*blo(u) + ctxL[2*(96+l)+1]*bhi(u); }
      acc += __shfl_xor(acc,1,32); acc += __shfl_xor(acc,2,32);
      acc += __shfl_xor(acc,4,32); acc += __shfl_xor(acc,8,32); acc += __shfl_xor(acc,16,32);
      if (l==0) zOwnL[jslot] += acc;
    }
    __syncthreads();                                      // B13
    // PH17: own-unit gates; wave-local hc publish + flag for step t+1
    if (tid < 64){
      if (tid < nu){
        float zi=zOwnL[tid*4+0], zf=zOwnL[tid*4+1], zg=zOwnL[tid*4+2], zo=zOwnL[tid*4+3];
        int u=u0+tid;
        float cc = sigf(zf)*cL[u] + sigf(zi)*tanhfast(zg);
        float hh = sigf(zo)*tanhfast(cc);
        ast64(hcp+u, (unsigned long long)__float_as_uint(hh)
                   | ((unsigned long long)__float_as_uint(cc)<<32));
        ws[OFF_HOUT + t*100 + u] = hh;
      }
      vm0();
      if (tid==0) ast64(FLG + (size_t)(64 + (t&1)*GW + w)*16, (unsigned long long)(sq+1));
    }
    // next iteration's PH1 poll + B1 is the inter-step sync
  }
}

// ---------------- kLoss: parallel logits + log-softmax over V ----------------
__global__ __launch_bounds__(256) void kLoss(const float* outW, const float* outb,
                                             const int* oid, float* ws)
{
  const int b=blockIdx.x, tid=threadIdx.x;
  const int tile=b>>1, hf=b&1, t0=tile*16;
  __shared__ float s_hn[16*100];
  __shared__ int   s_oid[16];
  __shared__ float red[4][16][3];
  for (int i=tid;i<1600;i+=256) s_hn[i]=ws[OFF_HOUT + t0*100 + i];
  if (tid<16) s_oid[tid]=oid[t0+tid];
  __syncthreads();
  const int VSPLIT = 25129;
  int vbeg = hf? VSPLIT : 0;
  int vend = hf? VOC : VSPLIT;
  float rm[16], rs[16], ol[16];
  #pragma unroll
  for (int tt=0;tt<16;tt++){ rm[tt]=-1e30f; rs[tt]=0.f; ol[tt]=-1e30f; }
  for (int v=vbeg+tid; v<vend; v+=256){
    const float4* wr = (const float4*)(outW + (size_t)v*100);
    float acc[16];
    #pragma unroll
    for (int tt=0;tt<16;tt++) acc[tt]=0.f;
    #pragma unroll 5
    for (int q=0;q<25;q++){
      float4 wv = wr[q];
      #pragma unroll
      for (int tt=0;tt<16;tt++){
        float4 hv = *(const float4*)(s_hn + tt*100 + q*4);
        acc[tt] += wv.x*hv.x + wv.y*hv.y + wv.z*hv.z + wv.w*hv.w;
      }
    }
    float bb = outb[v];
    #pragma unroll
    for (int tt=0;tt<16;tt++){
      float lg = acc[tt] + bb;
      if (v == s_oid[tt]) ol[tt] = fmaxf(ol[tt], lg);
      if (lg <= rm[tt]) rs[tt] += __expf(lg - rm[tt]);
      else { rs[tt] = rs[tt]*__expf(rm[tt]-lg) + 1.0f; rm[tt]=lg; }
    }
  }
  int wv2=tid>>6, ln=tid&63;
  #pragma unroll
  for (int tt=0;tt<16;tt++){
    float m=rm[tt], sv=rs[tt], o=ol[tt];
    for (int d=1;d<64;d<<=1){
      float om=__shfl_xor(m,d,64), os=__shfl_xor(sv,d,64), oo=__shfl_xor(o,d,64);
      float M2=fmaxf(m,om);
      sv = sv*__expf(m-M2) + os*__expf(om-M2);
      m=M2; o=fmaxf(o,oo);
    }
    if (ln==0){ red[wv2][tt][0]=m; red[wv2][tt][1]=sv; red[wv2][tt][2]=o; }
  }
  __syncthreads();
  if (tid<16){
    float M=-1e30f;
    for (int q=0;q<4;q++) M=fmaxf(M,red[q][tid][0]);
    float S=0.f, O=-1e30f;
    for (int q=0;q<4;q++){ S += red[q][tid][1]*__expf(red[q][tid][0]-M); O=fmaxf(O,red[q][tid][2]); }
    float* pb = ws + OFF_PB + (((tile*2)+hf)*16 + tid)*4;
    pb[0]=M; pb[1]=S; pb[2]=O;
  }
}

// ---------------- kFinal: combine halves, sum, scale ----------------
__global__ void kFinal(const float* weight, float* ws, float* out){
  __shared__ float red[256];
  int tid=threadIdx.x;
  float acc=0.f;
  for (int t=tid;t<TLEN;t+=256){
    int tile=t>>4, tt=t&15;
    const float* p0 = ws + OFF_PB + ((tile*2+0)*16+tt)*4;
    const float* p1 = ws + OFF_PB + ((tile*2+1)*16+tt)*4;
    float M=fmaxf(p0[0],p1[0]);
    float S=p0[1]*__expf(p0[0]-M) + p1[1]*__expf(p1[0]-M);
    float O=fmaxf(p0[2],p1[2]);
    acc += (M + logf(S)) - O;
  }
  red[tid]=acc; __syncthreads();
  for (int d=128; d>0; d>>=1){
    if (tid<d) red[tid]+=red[tid+d];
    __syncthreads();
  }
  if (tid==0) out[0]=red[0]*weight[0];
}

// ---------------- launch ----------------
extern "C" void kernel_launch(void* const* d_in, const int* in_sizes, int n_in,
                              void* d_out, int out_size, void* d_ws, size_t ws_size,
                              hipStream_t stream) {
  const int*   src      = (const int*)  d_in[0];
  const int*   tag      = (const int*)  d_in[1];
  const int*   oid      = (const int*)  d_in[2];
  const float* weight   = (const float*)d_in[3];
  const float* emb_char = (const float*)d_in[4];
  const float* emb_tag  = (const float*)d_in[5];
  const float* fWih=(const float*)d_in[6],  *fWhh=(const float*)d_in[7],  *fb=(const float*)d_in[8];
  const float* bWih=(const float*)d_in[9],  *bWhh=(const float*)d_in[10], *bb=(const float*)d_in[11];
  const float* tWih=(const float*)d_in[12], *tWhh=(const float*)d_in[13], *tb=(const float*)d_in[14];
  const float* dWih=(const float*)d_in[15], *dWhh=(const float*)d_in[16], *db=(const float*)d_in[17];
  const float* aw1 =(const float*)d_in[18], *aw2=(const float*)d_in[19];
  const float* aw3 =(const float*)d_in[20], *av =(const float*)d_in[21];
  const float* taw1=(const float*)d_in[22], *taw2=(const float*)d_in[23], *tavv=(const float*)d_in[24];
  const float* outW=(const float*)d_in[25], *outb=(const float*)d_in[26];
  float* ws  = (float*)d_ws;
  float* out = (float*)d_out;

  kInit<<<8, 256, 0, stream>>>(ws);
  kPrep<<<2*NN+TTAG+TLEN, 512, 0, stream>>>(src,tag,oid,emb_char,emb_tag,
                                            fWih,fb,bWih,bb,tWih,tb,dWih,db,ws);
  kEnc<<<3,512,0,stream>>>(fWhh,bWhh,tWhh,taw1,dWih,ws);
  kMid<<<NN,128,0,stream>>>(aw1,ws);
  kDec<<<GW,512,0,stream>>>(dWhh,dWih,aw2,aw3,av,taw2,tavv,ws);
  kLoss<<<256,256,0,stream>>>(outW,outb,oid,ws);
  kFinal<<<1,256,0,stream>>>(weight,ws,out);
}

// Round 10
// 26075.601 us; speedup vs baseline: 14.4179x; 1.3114x over previous
//
#include <hip/hip_runtime.h>
#include <math.h>

// ---------------- problem sizes ----------------
#define NN   2048   // source length
#define TLEN 2048   // target length
#define TTAG 64     // tags
#define VOC  50257
#define GW   32     // decoder blocks; each owns CHK source rows + 3-4 hidden units
#define CHK  64     // source rows per block
#define RECU 80     // u64 stride per record (68 used)
static_assert(GW * CHK == NN, "chunking");

// ---------------- workspace layout (float units) ----------------
#define OFF_XF    0                          // NN*400
#define OFF_XB    (OFF_XF  + NN*400)         // NN*400
#define OFF_TGX   (OFF_XB  + NN*400)         // TTAG*400
#define OFF_PEW   (OFF_TGX + TTAG*400)       // TLEN*400
#define OFF_ENC   (OFF_PEW + TLEN*400)       // NN*200
#define OFF_W1DT  (OFF_ENC + NN*200)         // NN*100
#define OFF_TAGV  (OFF_W1DT+ NN*100)         // TTAG*100
#define OFF_TGW1  (OFF_TAGV+ TTAG*100)       // TTAG*100
#define OFF_TGW   (OFF_TGW1+ TTAG*100)       // TTAG*400
#define OFF_HOUT  (OFF_TGW + TTAG*400)       // TLEN*100
#define OFF_REC   (OFF_HOUT+ TLEN*100)       // 2*GW*RECU u64
#define OFF_HC    (OFF_REC + 2*GW*RECU*2)    // 2*128 u64
#define OFF_FLG   (OFF_HC  + 2*128*2)        // 2048 u64 flags (128B-spread)
#define OFF_PB    (OFF_FLG + 4096)           // loss partials

// record u64 words: [0..49] ctxp 4xbf16/word, [50..65] scores 4xbf16/word (64 rows),
//   [66]={m f32 | S f32}, [67]={amax f32 | idx}
// hc buffer b: word u = {h[u] f32 | c[u] f32}
// Protocol: data stores (system write-through) -> wave-local s_waitcnt vmcnt(0) ->
// one flag store by same wave. Consumer: ONE wave spins on flags via __all
// (no block barrier per poll round) -> single release barrier -> bulk read.

// ---------------- helpers ----------------
__device__ __forceinline__ float rcpf(float x){ return __builtin_amdgcn_rcpf(x); }
__device__ __forceinline__ float sigf(float x){ return rcpf(1.0f+__expf(-x)); }
__device__ __forceinline__ float tanhfast(float x){
  float e = __expf(2.0f*x);
  return 1.0f - 2.0f*rcpf(e+1.0f);
}
__device__ __forceinline__ unsigned short f2b(float x){
  unsigned b=__float_as_uint(x);
  return (unsigned short)((b + 0x7fffu + ((b>>16)&1u))>>16);
}
__device__ __forceinline__ unsigned pk2(float a,float b){ return (unsigned)f2b(a) | ((unsigned)f2b(b)<<16); }
__device__ __forceinline__ float blo(unsigned u){ return __uint_as_float(u<<16); }
__device__ __forceinline__ float bhi(unsigned u){ return __uint_as_float(u&0xffff0000u); }

__device__ __forceinline__ unsigned long long ald64(const unsigned long long* p){
  return __hip_atomic_load(p,__ATOMIC_RELAXED,__HIP_MEMORY_SCOPE_SYSTEM);
}
__device__ __forceinline__ void ast64(unsigned long long* p, unsigned long long v){
  __hip_atomic_store(p,v,__ATOMIC_RELAXED,__HIP_MEMORY_SCOPE_SYSTEM);
}
__device__ __forceinline__ void vm0(){ asm volatile("s_waitcnt vmcnt(0)" ::: "memory"); }

// ---------------- kInit: zero flag region (every launch / replay) ----------------
__global__ void kInit(float* ws){
  unsigned long long* f = (unsigned long long*)(ws + OFF_FLG);
  int i = blockIdx.x*256 + threadIdx.x;
  if (i < 2048) ast64(f+i, 0ull);
}

// ---------------- kPrep: all input-side GEMVs (parallel) ----------------
__global__ __launch_bounds__(512) void kPrep(
    const int* src, const int* tag, const int* oid,
    const float* emb_char, const float* emb_tag,
    const float* fWih, const float* fb,
    const float* bWih, const float* bb,
    const float* tWih, const float* tb,
    const float* dWih, const float* db, float* ws)
{
  int r = blockIdx.x, j = threadIdx.x;
  if (j >= 400) return;
  if (r < NN) {
    const float* e = emb_char + (size_t)src[r]*32;
    const float* Wr = fWih + j*32;
    float a = fb[j];
    #pragma unroll
    for (int q=0;q<32;q++) a += e[q]*Wr[q];
    ws[OFF_XF + r*400 + j] = a;
  } else if (r < 2*NN) {
    int n = r - NN;
    const float* e = emb_char + (size_t)src[n]*32;
    const float* Wr = bWih + j*32;
    float a = bb[j];
    #pragma unroll
    for (int q=0;q<32;q++) a += e[q]*Wr[q];
    ws[OFF_XB + n*400 + j] = a;
  } else if (r < 2*NN + TTAG) {
    int s = r - 2*NN;
    const float* e = emb_tag + (size_t)tag[s]*32;
    const float* Wr = tWih + j*32;
    float a = tb[j];
    #pragma unroll
    for (int q=0;q<32;q++) a += e[q]*Wr[q];
    ws[OFF_TGX + s*400 + j] = a;
  } else {
    int t = r - (2*NN + TTAG);
    int pid = (t==0) ? 0 : oid[t-1];
    const float* e = emb_char + (size_t)pid*32;
    const float* Wr = dWih + (size_t)j*332 + 300;
    float a = db[j];
    #pragma unroll
    for (int q=0;q<32;q++) a += e[q]*Wr[q];
    ws[OFF_PEW + t*400 + j] = a;
  }
}

// ---------------- kEnc: sequential LSTM scans (3 independent blocks) ----------------
// NOTE: z-loops are FULLY unrolled so whh[100] stays in VGPRs (runtime-indexed
// register arrays go to scratch — that was 10 ms of the R9 profile).
struct EncShared {
  float tvs[TTAG*100];
  float sa [TTAG*64];
  float hbuf[100];
  float zbuf[400];
};

__device__ void lstm_block(const float* Whh, const float* xbase, float* ws,
                           int reverse, int col, EncShared* sh)
{
  int tid = threadIdx.x;
  float whh[100];
  if (tid < 400){
    #pragma unroll
    for (int k=0;k<100;k++) whh[k] = Whh[tid*100+k];
  }
  float c = 0.f;
  if (tid < 100) sh->hbuf[tid] = 0.f;
  __syncthreads();
  for (int i=0;i<NN;i++){
    int n = reverse ? (NN-1-i) : i;
    if (tid < 400){
      float z = xbase[n*400+tid];
      #pragma unroll
      for (int k=0;k<100;k++) z += whh[k]*sh->hbuf[k];
      sh->zbuf[tid] = z;
    }
    __syncthreads();
    if (tid < 100){
      float zi=sh->zbuf[tid], zf=sh->zbuf[tid+100], zg=sh->zbuf[tid+200], zo=sh->zbuf[tid+300];
      c = sigf(zf)*c + sigf(zi)*tanhfast(zg);
      float h = sigf(zo)*tanhfast(c);
      sh->hbuf[tid] = h;
      ws[OFF_ENC + n*200 + col + tid] = h;
    }
    __syncthreads();
  }
}

__global__ __launch_bounds__(512,1) void kEnc(
    const float* fWhh, const float* bWhh, const float* tWhh,
    const float* taw1, const float* dWih, float* ws)
{
  __shared__ EncShared sh;
  int b = blockIdx.x, tid = threadIdx.x;
  if (b == 0){ lstm_block(fWhh, ws+OFF_XF, ws, 0, 0,   &sh); return; }
  if (b == 1){ lstm_block(bWhh, ws+OFF_XB, ws, 1, 100, &sh); return; }

  // ---- block 2: tag LSTM + self-attn + tagv-derived tables ----
  {
    float whh[100];
    if (tid<400){
      #pragma unroll
      for (int k=0;k<100;k++) whh[k] = tWhh[tid*100+k];
    }
    float c = 0.f;
    if (tid<100) sh.hbuf[tid] = 0.f;
    __syncthreads();
    for (int s=0;s<TTAG;s++){
      if (tid<400){
        float z = ws[OFF_TGX + s*400 + tid];
        #pragma unroll
        for (int k=0;k<100;k++) z += whh[k]*sh.hbuf[k];
        sh.zbuf[tid] = z;
      }
      __syncthreads();
      if (tid<100){
        float zi=sh.zbuf[tid], zf=sh.zbuf[tid+100], zg=sh.zbuf[tid+200], zo=sh.zbuf[tid+300];
        c = sigf(zf)*c + sigf(zi)*tanhfast(zg);
        float h = sigf(zo)*tanhfast(c);
        sh.hbuf[tid] = h;
        sh.tvs[s*100+tid] = h;
      }
      __syncthreads();
    }
  }
  for (int idx=tid; idx<TTAG*TTAG; idx+=512){
    int s=idx>>6, t2=idx&63;
    float a=0.f;
    #pragma unroll 10
    for (int h=0;h<100;h++) a += sh.tvs[s*100+h]*sh.tvs[t2*100+h];
    sh.sa[idx]=a;
  }
  __syncthreads();
  if (tid<TTAG){
    float m=-1e30f;
    for (int t2=0;t2<64;t2++) m = fmaxf(m, sh.sa[tid*64+t2]);
    float sum=0.f;
    for (int t2=0;t2<64;t2++){ float e=__expf(sh.sa[tid*64+t2]-m); sh.sa[tid*64+t2]=e; sum+=e; }
    float r=1.f/sum;
    for (int t2=0;t2<64;t2++) sh.sa[tid*64+t2]*=r;
  }
  __syncthreads();
  float tvloc[13]; int cnt=0;
  for (int idx=tid; idx<TTAG*100; idx+=512){
    int t2=idx/100, hh=idx%100;
    float a = sh.tvs[t2*100+hh];
    for (int s=0;s<64;s++) a += sh.tvs[s*100+hh]*sh.sa[s*64+t2];
    tvloc[cnt++]=a;
    ws[OFF_TAGV+idx]=a;
  }
  __syncthreads();
  float* tagvs = sh.sa;
  cnt=0;
  for (int idx=tid; idx<TTAG*100; idx+=512) tagvs[idx]=tvloc[cnt++];
  __syncthreads();
  for (int idx=tid; idx<TTAG*100; idx+=512){
    int s=idx/100, k=idx%100;
    float a=0.f;
    #pragma unroll 10
    for (int h=0;h<100;h++) a += tagvs[s*100+h]*taw1[k*100+h];
    ws[OFF_TGW1+idx]=a;
  }
  for (int idx=tid; idx<TTAG*400; idx+=512){
    int s=idx/400, j=idx%400;
    const float* Wr = dWih + (size_t)j*332 + 200;
    float a=0.f;
    #pragma unroll 10
    for (int h=0;h<100;h++) a += tagvs[s*100+h]*Wr[h];
    ws[OFF_TGW+idx]=a;
  }
}

// ---------------- kMid: w1dt = enc @ attn_w1.T ----------------
__global__ void kMid(const float* aw1, float* ws){
  __shared__ float er[200];
  int n=blockIdx.x, tid=threadIdx.x;
  for (int i=tid;i<200;i+=128) er[i]=ws[OFF_ENC+n*200+i];
  __syncthreads();
  if (tid<100){
    const float* Wr = aw1 + tid*200;
    float a=0.f;
    #pragma unroll 8
    for (int d=0;d<200;d++) a += er[d]*Wr[d];
    ws[OFF_W1DT + n*100 + tid]=a;
  }
}

// ---------------- kDec: de-replicated decoder, wave-local sync machinery ----------------
__global__ __launch_bounds__(512) void kDec(
    const float* dWhh, const float* dWih,
    const float* aw2, const float* aw3, const float* av,
    const float* taw2, const float* tav, float* ws)
{
  // padded strides: 101 per 100-wide row, 51 per 50-wide row (bank-conflict fix)
  __shared__ unsigned aw2L[100*101];
  __shared__ unsigned tw2L[100*101];
  __shared__ unsigned tw1L[TTAG*51];
  __shared__ unsigned tagvL[TTAG*51];
  __shared__ unsigned w1L[CHK*51];
  __shared__ unsigned encL[CHK*101];
  __shared__ float tavL[100], avL[100], aw3L[500];
  __shared__ float hL[100], cL[100], tcL[100], tsaL[100], nsL[200];
  __shared__ float uL[TTAG], tawL[TTAG];
  __shared__ float ctxL[200], a23L[100], ctxpL[200];
  __shared__ float srowL[CHK], eRL[CHK];
  __shared__ float sclL[GW];
  __shared__ float zOwnL[16];
  __shared__ float hdrL[4];
  __shared__ float prevL[5];
  __shared__ float MS[2];
  __shared__ int   amiL;

  const int tid = threadIdx.x;
  const int w   = blockIdx.x;
  unsigned long long* REC = (unsigned long long*)(ws + OFF_REC);
  unsigned long long* HC  = (unsigned long long*)(ws + OFF_HC);
  unsigned long long* FLG = (unsigned long long*)(ws + OFF_FLG);

  // ---- hidden-unit ownership: blocks 0..3 -> 4 units, 4..31 -> 3 units ----
  const int nu = (w<4)? 4 : 3;
  const int u0 = (w<4)? w*4 : 16 + (w-4)*3;
  const int nact = nu*4;
  const int jslot = tid>>5, l = tid&31;

  // ---- tiny per-thread weight registers (own gate-rows only) ----
  unsigned wca0=0,wca1=0,wca2=0,wca3=0, wha0=0,wha1=0, wta0=0,wta1=0;
  int row=0;
  if (jslot < nact){
    row = (jslot&3)*100 + u0 + (jslot>>2);
    const float* Wr = dWih + (size_t)row*332;
    wca0=pk2(Wr[2*l],Wr[2*l+1]);
    wca1=pk2(Wr[2*(32+l)],Wr[2*(32+l)+1]);
    wca2=pk2(Wr[2*(64+l)],Wr[2*(64+l)+1]);
    if (l<4) wca3=pk2(Wr[2*(96+l)],Wr[2*(96+l)+1]);
    const float* Wh = dWhh + (size_t)row*100;
    wha0=pk2(Wh[2*l],Wh[2*l+1]);
    if (l<18) wha1=pk2(Wh[2*(32+l)],Wh[2*(32+l)+1]);
    const float* Wt = Wr + 200;
    wta0=pk2(Wt[2*l],Wt[2*l+1]);
    if (l<18) wta1=pk2(Wt[2*(32+l)],Wt[2*(32+l)+1]);
  }
  // ---- LDS preload (padded strides) ----
  for (int i=tid;i<100*100;i+=512){ int k=i/100,p=i%100; aw2L[k*101+p]=pk2(aw2 [k*200+2*p], aw2 [k*200+2*p+1]); }
  for (int i=tid;i<100*100;i+=512){ int k=i/100,p=i%100; tw2L[k*101+p]=pk2(taw2[k*200+2*p], taw2[k*200+2*p+1]); }
  for (int i=tid;i<TTAG*50;i+=512){ int s=i/50,p=i%50; tw1L[s*51+p]=pk2(ws[OFF_TGW1+s*100+2*p], ws[OFF_TGW1+s*100+2*p+1]); }
  for (int i=tid;i<TTAG*50;i+=512){ int s=i/50,p=i%50; tagvL[s*51+p]=pk2(ws[OFF_TAGV+s*100+2*p], ws[OFF_TAGV+s*100+2*p+1]); }
  for (int i=tid;i<CHK*50;i+=512){ int r=i/50,p=i%50; w1L[r*51+p]=pk2(ws[OFF_W1DT+(w*CHK+r)*100+2*p], ws[OFF_W1DT+(w*CHK+r)*100+2*p+1]); }
  for (int i=tid;i<CHK*100;i+=512){ int r=i/100,p=i%100; encL[r*101+p]=pk2(ws[OFF_ENC+(w*CHK+r)*200+2*p], ws[OFF_ENC+(w*CHK+r)*200+2*p+1]); }
  if (tid<100){ tavL[tid]=tav[tid]; avL[tid]=av[tid]; }
  for (int i=tid;i<500;i+=512) aw3L[i]=aw3[i];
  if (tid<5)   prevL[tid]=0.f;
  if (tid<200) ctxL[tid]=ws[OFF_ENC + 2047*200 + tid];   // enc_last for init
  __syncthreads();

  // ---- init: own-row z0 -> h0,c0 -> publish hc buffer 1 + flag=1 (wave-local) ----
  if (jslot < nact){
    float acc=0.f;
    { unsigned u=wca0; acc += ctxL[2*l]*blo(u) + ctxL[2*l+1]*bhi(u); }
    { unsigned u=wca1; acc += ctxL[2*(32+l)]*blo(u) + ctxL[2*(32+l)+1]*bhi(u); }
    { unsigned u=wca2; acc += ctxL[2*(64+l)]*blo(u) + ctxL[2*(64+l)+1]*bhi(u); }
    if (l<4){ unsigned u=wca3; acc += ctxL[2*(96+l)]*blo(u) + ctxL[2*(96+l)+1]*bhi(u); }
    acc += __shfl_xor(acc,1,32); acc += __shfl_xor(acc,2,32);
    acc += __shfl_xor(acc,4,32); acc += __shfl_xor(acc,8,32); acc += __shfl_xor(acc,16,32);
    if (l==0) zOwnL[jslot] = acc + ws[OFF_TGW + 63*400 + row] + ws[OFF_PEW + row];
  }
  __syncthreads();
  if (tid < 64){
    if (tid < nu){
      float zi=zOwnL[tid*4+0], zg=zOwnL[tid*4+2], zo=zOwnL[tid*4+3];
      float cc = sigf(zi)*tanhfast(zg);
      float hh = sigf(zo)*tanhfast(cc);
      int u = u0+tid;
      ast64(HC + 128 + u, (unsigned long long)__float_as_uint(hh)
                        | ((unsigned long long)__float_as_uint(cc)<<32));
    }
    vm0();
    if (tid==0) ast64(FLG + (size_t)(64 + GW + w)*16, 1ull);
  }

  for (int t=0; t<TLEN; ++t){
    const unsigned sq = (unsigned)(t+1);
    unsigned long long* slot = REC + (size_t)(t&1)*GW*RECU;
    unsigned long long* hcg  = HC + (size_t)((t+1)&1)*128;
    unsigned long long* hcp  = HC + (size_t)(t&1)*128;
    unsigned long long* fr   = FLG + (size_t)(t&1)*GW*16;
    unsigned long long* fhg  = FLG + (size_t)(64 + ((t+1)&1)*GW)*16;

    // PH1: wave 0 polls hc flags (__all) + reads h,c into LDS; single release barrier
    if (tid < 64){
      int ok = (tid >= GW) ? 1 : 0;
      for(;;){
        if (!ok) ok = ((unsigned)ald64(fhg + (size_t)tid*16) == sq);
        if (__all(ok)) break;
      }
      if (tid < 50){
        unsigned long long v0 = ald64(hcg + 2*tid), v1 = ald64(hcg + 2*tid + 1);
        hL[2*tid]   = __uint_as_float((unsigned)v0); cL[2*tid]   = __uint_as_float((unsigned)(v0>>32));
        hL[2*tid+1] = __uint_as_float((unsigned)v1); cL[2*tid+1] = __uint_as_float((unsigned)(v1>>32));
      }
    }
    __syncthreads();                                      // B1
    // PH2: tsa[k] = state · tag_attn_w2[k]
    if (tid<400){
      int k=tid>>2, q=tid&3, off=q*50;
      const float* sb = (off<100)? (hL+off) : (cL+(off-100));
      float acc=0.f;
      #pragma unroll
      for (int i=0;i<25;i++){ unsigned u=tw2L[k*101+q*25+i]; acc += sb[2*i]*blo(u) + sb[2*i+1]*bhi(u); }
      acc += __shfl_xor(acc,1,4); acc += __shfl_xor(acc,2,4);
      if (q==0) tsaL[k]=acc;
    }
    __syncthreads();                                      // B2
    { // PH3: tag scores (8 thr/tag)
      int sp=tid>>3, l8=tid&7;
      float acc=0.f;
      for (int k=l8;k<100;k+=8){
        unsigned u=tw1L[sp*51+(k>>1)];
        float w1v=(k&1)? bhi(u) : blo(u);
        acc += tanhfast(w1v + tsaL[k]) * tavL[k];
      }
      acc += __shfl_xor(acc,1,8); acc += __shfl_xor(acc,2,8); acc += __shfl_xor(acc,4,8);
      if (l8==0) uL[sp]=acc;
    }
    __syncthreads();                                      // B3
    if (tid<64){ // PH4: softmax over 64 tags
      float v=uL[tid], m=v;
      for (int d=1;d<64;d<<=1) m=fmaxf(m,__shfl_xor(m,d,64));
      float e=__expf(v-m), ssum=e;
      for (int d=1;d<64;d<<=1) ssum+=__shfl_xor(ssum,d,64);
      tawL[tid]=e*rcpf(ssum);
    }
    __syncthreads();                                      // B4
    if (tid<400){ // PH5: tag_ctx (4 thr/hh) + fold ns
      int hh=tid>>2, q=tid&3;
      float acc=0.f;
      #pragma unroll
      for (int i=0;i<16;i++){
        int s=q*16+i;
        unsigned u=tagvL[s*51+(hh>>1)];
        acc += tawL[s]*((hh&1)? bhi(u):blo(u));
      }
      acc += __shfl_xor(acc,1,4); acc += __shfl_xor(acc,2,4);
      if (q==0){ tcL[hh]=acc; nsL[hh]=hL[hh]+acc; nsL[100+hh]=cL[hh]+acc; }
    }
    __syncthreads();                                      // B5
    if (tid<400){ // PH6: a23[k]
      int k=tid>>2, q=tid&3, off=q*50;
      float acc=0.f;
      #pragma unroll
      for (int i=0;i<25;i++){ unsigned u=aw2L[k*101+q*25+i]; acc += nsL[off+2*i]*blo(u) + nsL[off+2*i+1]*bhi(u); }
      acc += __shfl_xor(acc,1,4); acc += __shfl_xor(acc,2,4);
      if (q==0){
        float a3=0.f;
        #pragma unroll
        for (int i=0;i<5;i++) a3 += prevL[i]*aw3L[k*5+i];
        a23L[k]=acc+a3;
      }
    }
    __syncthreads();                                      // B6
    { // PH7: own 64 rows' scores (8 lanes/row)
      int r=tid>>3, l8=tid&7;
      float acc=0.f;
      for (int k=l8;k<100;k+=8){
        unsigned u=w1L[r*51+(k>>1)];
        float w1v=(k&1)? bhi(u) : blo(u);
        acc += tanhfast(w1v + a23L[k]) * avL[k];
      }
      acc += __shfl_xor(acc,1,8); acc += __shfl_xor(acc,2,8); acc += __shfl_xor(acc,4,8);
      if (l8==0) srowL[r]=acc;
    }
    __syncthreads();                                      // B7
    if (tid<64){ // PH8: local stats + argmax over own 64 rows
      float v=srowL[tid], m=v;
      for (int d=1;d<64;d<<=1) m=fmaxf(m,__shfl_xor(m,d,64));
      float e=__expf(v-m); eRL[tid]=e;
      float Ss=e;
      for (int d=1;d<64;d<<=1) Ss+=__shfl_xor(Ss,d,64);
      float bv=v; int bi=w*CHK+tid;
      for (int d=1;d<64;d<<=1){
        float ov=__shfl_xor(bv,d,64); int oi=__shfl_xor(bi,d,64);
        if (ov>bv || (ov==bv && oi<bi)){ bv=ov; bi=oi; }
      }
      if (tid==0){ hdrL[0]=m; hdrL[1]=Ss; hdrL[2]=bv; ((int*)hdrL)[3]=bi; }
    }
    __syncthreads();                                      // B8
    if (tid<400){ // PH9: ctx partial over own rows (2 thr/d)
      int d=tid>>1, hf=tid&1;
      float acc=0.f;
      #pragma unroll 8
      for (int i=0;i<32;i++){
        int rr=hf*32+i;
        unsigned u=encL[rr*101+(d>>1)];
        acc += eRL[rr]*((d&1)? bhi(u):blo(u));
      }
      acc += __shfl_xor(acc,1,2);
      if (hf==0) ctxpL[d]=acc;
    }
    __syncthreads();                                      // B9

    // PH10/11: wave 7 publishes record (wave-local vm0+flag) then its zpre;
    //          waves 0-6 do their zpre rows.
    #define ZPRE_ROW() do{ \
      if (jslot < nact){ \
        float acc=0.f; \
        { unsigned u=wha0; acc += hL[2*l]*blo(u) + hL[2*l+1]*bhi(u); } \
        if (l<18){ unsigned u=wha1; acc += hL[2*(32+l)]*blo(u) + hL[2*(32+l)+1]*bhi(u); } \
        { unsigned u=wta0; acc += tcL[2*l]*blo(u) + tcL[2*l+1]*bhi(u); } \
        if (l<18){ unsigned u=wta1; acc += tcL[2*(32+l)]*blo(u) + tcL[2*(32+l)+1]*bhi(u); } \
        acc += __shfl_xor(acc,1,32); acc += __shfl_xor(acc,2,32); \
        acc += __shfl_xor(acc,4,32); acc += __shfl_xor(acc,8,32); acc += __shfl_xor(acc,16,32); \
        if (l==0) zOwnL[jslot] = acc + ws[OFF_PEW + t*400 + row]; \
      } \
    }while(0)

    if (tid < 448){
      ZPRE_ROW();
    } else {
      int lane = tid-448;
      unsigned long long* rp = slot + (size_t)w*RECU;
      if (lane < 50)
        ast64(rp+lane, (unsigned long long)pk2(ctxpL[4*lane],ctxpL[4*lane+1])
                     | ((unsigned long long)pk2(ctxpL[4*lane+2],ctxpL[4*lane+3])<<32));
      else { int j=lane-50;  // j=0..13 -> words 50..63
        ast64(rp+lane, (unsigned long long)pk2(srowL[4*j],srowL[4*j+1])
                     | ((unsigned long long)pk2(srowL[4*j+2],srowL[4*j+3])<<32)); }
      if (lane < 2){ int j=14+lane;  // words 64,65
        ast64(rp+64+lane, (unsigned long long)pk2(srowL[4*j],srowL[4*j+1])
                        | ((unsigned long long)pk2(srowL[4*j+2],srowL[4*j+3])<<32)); }
      else if (lane==2)
        ast64(rp+66, (unsigned long long)__float_as_uint(hdrL[0])
                   | ((unsigned long long)__float_as_uint(hdrL[1])<<32));
      else if (lane==3)
        ast64(rp+67, (unsigned long long)__float_as_uint(hdrL[2])
                   | ((unsigned long long)(unsigned)((int*)hdrL)[3]<<32));
      vm0();
      if (lane==0) ast64(fr + (size_t)w*16, (unsigned long long)sq);
      ZPRE_ROW();   // jslot 14,15 (active only for blocks 0-3)
    }

    // PH12: wave 0 polls record flags (__all); single release barrier
    if (tid < 64){
      int ok = (tid >= GW) ? 1 : 0;
      for(;;){
        if (!ok) ok = ((unsigned)ald64(fr + (size_t)tid*16) == sq);
        if (__all(ok)) break;
      }
    }
    __syncthreads();                                      // B10
    // PH13: waves 0-6 bulk-read ctx words; wave 7 reads hdrs + in-wave reduce
    unsigned long long pay[4];
    if (tid<400){
      int dw=tid>>3, s8=tid&7;
      #pragma unroll
      for (int i=0;i<4;i++) pay[i]=ald64(slot + (size_t)(s8*4+i)*RECU + dw);
    } else if (tid>=448){
      int lane=tid-448, r=lane&31, up=lane>>5;
      unsigned long long v = ald64(slot + (size_t)r*RECU + 66 + up);
      float x0 = __uint_as_float((unsigned)v);            // m (lo) or av (hi half's lo)
      float x1 = __uint_as_float((unsigned)(v>>32));      // S or ai-bits
      int   xi = (int)(unsigned)(v>>32);
      float pv = x0; int pi = xi;
      #pragma unroll
      for (int d=1;d<32;d<<=1){
        float ov=__shfl_xor(pv,d,32); int oi=__shfl_xor(pi,d,32);
        if (up){ if (ov>pv || (ov==pv && oi<pi)){ pv=ov; pi=oi; } }
        else   { pv = fmaxf(pv,ov); }
      }
      if (!up){
        float sc = __expf(x0 - pv);                       // pv = M
        sclL[r] = sc;
        float ss = sc * x1;
        #pragma unroll
        for (int d=1;d<32;d<<=1) ss += __shfl_xor(ss,d,32);
        if (r==0){ MS[0]=pv; MS[1]=ss; }
      } else {
        if (r==0) amiL = pi;
      }
    }
    __syncthreads();                                      // B11
    // PH15b: ctx assemble (shfl over 8 lanes)
    if (tid<400){
      float rS = rcpf(MS[1]);
      int dw=tid>>3, s8=tid&7;
      float c0=0.f,c1=0.f,c2=0.f,c3=0.f;
      #pragma unroll
      for (int i=0;i<4;i++){
        float sc=sclL[s8*4+i];
        unsigned lo=(unsigned)pay[i], hi=(unsigned)(pay[i]>>32);
        c0 += blo(lo)*sc; c1 += bhi(lo)*sc;
        c2 += blo(hi)*sc; c3 += bhi(hi)*sc;
      }
      #pragma unroll
      for (int d=1;d<8;d<<=1){
        c0 += __shfl_xor(c0,d,8); c1 += __shfl_xor(c1,d,8);
        c2 += __shfl_xor(c2,d,8); c3 += __shfl_xor(c3,d,8);
      }
      if (s8==0){
        ctxL[4*dw+0]=c0*rS; ctxL[4*dw+1]=c1*rS;
        ctxL[4*dw+2]=c2*rS; ctxL[4*dw+3]=c3*rS;
      }
    }
    __syncthreads();                                      // B12
    // PH16: own-row z += ctx·Wihc
    if (jslot < nact){
      float acc=0.f;
      { unsigned u=wca0; acc += ctxL[2*l]*blo(u) + ctxL[2*l+1]*bhi(u); }
      { unsigned u=wca1; acc += ctxL[2*(32+l)]*blo(u) + ctxL[2*(32+l)+1]*bhi(u); }
      { unsigned u=wca2; acc += ctxL[2*(64+l)]*blo(u) + ctxL[2*(64+l)+1]*bhi(u); }
      if (l<4){ unsigned u=wca3; acc += ctxL[2*(96+l)]*blo(u) + ctxL[2*(96+l)+1]*bhi(u); }
      acc += __shfl_xor(acc,1,32); acc += __shfl_xor(acc,2,32);
      acc += __shfl_xor(acc,4,32); acc += __shfl_xor(acc,8,32); acc += __shfl_xor(acc,16,32);
      if (l==0) zOwnL[jslot] += acc;
    }
    __syncthreads();                                      // B13
    // PH15a (MOVED): next-step prev window — 5 system loads issued by wave 6,
    // overlapping PH17's publish + the inter-step hc hop. Consumed at next
    // step's PH6 (ordered by next B1). MS/amiL/slot stable until next B10/B11.
    if (tid>=440 && tid<445){
      int i=tid-440;
      int st = amiL-1; st = st<0?0:st; st = st>NN-6?NN-6:st;
      int g = st+i, r=g>>6, lr=g&63;
      unsigned long long v = ald64(slot + (size_t)r*RECU + 50 + (lr>>2));
      unsigned half = (lr&2)? (unsigned)(v>>32) : (unsigned)v;
      float sc = (lr&1)? bhi(half) : blo(half);
      prevL[i] = __expf(sc - MS[0]) * rcpf(MS[1]);
    }
    // PH17: own-unit gates; wave-local hc publish + flag for step t+1
    if (tid < 64){
      if (tid < nu){
        float zi=zOwnL[tid*4+0], zf=zOwnL[tid*4+1], zg=zOwnL[tid*4+2], zo=zOwnL[tid*4+3];
        int u=u0+tid;
        float cc = sigf(zf)*cL[u] + sigf(zi)*tanhfast(zg);
        float hh = sigf(zo)*tanhfast(cc);
        ast64(hcp+u, (unsigned long long)__float_as_uint(hh)
                   | ((unsigned long long)__float_as_uint(cc)<<32));
        ws[OFF_HOUT + t*100 + u] = hh;
      }
      vm0();
      if (tid==0) ast64(FLG + (size_t)(64 + (t&1)*GW + w)*16, (unsigned long long)(sq+1));
    }
    // next iteration's PH1 poll + B1 is the inter-step sync
  }
}

// ---------------- kLoss: parallel logits + log-softmax over V ----------------
__global__ __launch_bounds__(256) void kLoss(const float* outW, const float* outb,
                                             const int* oid, float* ws)
{
  const int b=blockIdx.x, tid=threadIdx.x;
  const int tile=b>>1, hf=b&1, t0=tile*16;
  __shared__ float s_hn[16*100];
  __shared__ int   s_oid[16];
  __shared__ float red[4][16][3];
  for (int i=tid;i<1600;i+=256) s_hn[i]=ws[OFF_HOUT + t0*100 + i];
  if (tid<16) s_oid[tid]=oid[t0+tid];
  __syncthreads();
  const int VSPLIT = 25129;
  int vbeg = hf? VSPLIT : 0;
  int vend = hf? VOC : VSPLIT;
  float rm[16], rs[16], ol[16];
  #pragma unroll
  for (int tt=0;tt<16;tt++){ rm[tt]=-1e30f; rs[tt]=0.f; ol[tt]=-1e30f; }
  for (int v=vbeg+tid; v<vend; v+=256){
    const float4* wr = (const float4*)(outW + (size_t)v*100);
    float acc[16];
    #pragma unroll
    for (int tt=0;tt<16;tt++) acc[tt]=0.f;
    #pragma unroll 5
    for (int q=0;q<25;q++){
      float4 wv = wr[q];
      #pragma unroll
      for (int tt=0;tt<16;tt++){
        float4 hv = *(const float4*)(s_hn + tt*100 + q*4);
        acc[tt] += wv.x*hv.x + wv.y*hv.y + wv.z*hv.z + wv.w*hv.w;
      }
    }
    float bb = outb[v];
    #pragma unroll
    for (int tt=0;tt<16;tt++){
      float lg = acc[tt] + bb;
      if (v == s_oid[tt]) ol[tt] = fmaxf(ol[tt], lg);
      if (lg <= rm[tt]) rs[tt] += __expf(lg - rm[tt]);
      else { rs[tt] = rs[tt]*__expf(rm[tt]-lg) + 1.0f; rm[tt]=lg; }
    }
  }
  int wv2=tid>>6, ln=tid&63;
  #pragma unroll
  for (int tt=0;tt<16;tt++){
    float m=rm[tt], sv=rs[tt], o=ol[tt];
    for (int d=1;d<64;d<<=1){
      float om=__shfl_xor(m,d,64), os=__shfl_xor(sv,d,64), oo=__shfl_xor(o,d,64);
      float M2=fmaxf(m,om);
      sv = sv*__expf(m-M2) + os*__expf(om-M2);
      m=M2; o=fmaxf(o,oo);
    }
    if (ln==0){ red[wv2][tt][0]=m; red[wv2][tt][1]=sv; red[wv2][tt][2]=o; }
  }
  __syncthreads();
  if (tid<16){
    float M=-1e30f;
    for (int q=0;q<4;q++) M=fmaxf(M,red[q][tid][0]);
    float S=0.f, O=-1e30f;
    for (int q=0;q<4;q++){ S += red[q][tid][1]*__expf(red[q][tid][0]-M); O=fmaxf(O,red[q][tid][2]); }
    float* pb = ws + OFF_PB + (((tile*2)+hf)*16 + tid)*4;
    pb[0]=M; pb[1]=S; pb[2]=O;
  }
}

// ---------------- kFinal: combine halves, sum, scale ----------------
__global__ void kFinal(const float* weight, float* ws, float* out){
  __shared__ float red[256];
  int tid=threadIdx.x;
  float acc=0.f;
  for (int t=tid;t<TLEN;t+=256){
    int tile=t>>4, tt=t&15;
    const float* p0 = ws + OFF_PB + ((tile*2+0)*16+tt)*4;
    const float* p1 = ws + OFF_PB + ((tile*2+1)*16+tt)*4;
    float M=fmaxf(p0[0],p1[0]);
    float S=p0[1]*__expf(p0[0]-M) + p1[1]*__expf(p1[0]-M);
    float O=fmaxf(p0[2],p1[2]);
    acc += (M + logf(S)) - O;
  }
  red[tid]=acc; __syncthreads();
  for (int d=128; d>0; d>>=1){
    if (tid<d) red[tid]+=red[tid+d];
    __syncthreads();
  }
  if (tid==0) out[0]=red[0]*weight[0];
}

// ---------------- launch ----------------
extern "C" void kernel_launch(void* const* d_in, const int* in_sizes, int n_in,
                              void* d_out, int out_size, void* d_ws, size_t ws_size,
                              hipStream_t stream) {
  const int*   src      = (const int*)  d_in[0];
  const int*   tag      = (const int*)  d_in[1];
  const int*   oid      = (const int*)  d_in[2];
  const float* weight   = (const float*)d_in[3];
  const float* emb_char = (const float*)d_in[4];
  const float* emb_tag  = (const float*)d_in[5];
  const float* fWih=(const float*)d_in[6],  *fWhh=(const float*)d_in[7],  *fb=(const float*)d_in[8];
  const float* bWih=(const float*)d_in[9],  *bWhh=(const float*)d_in[10], *bb=(const float*)d_in[11];
  const float* tWih=(const float*)d_in[12], *tWhh=(const float*)d_in[13], *tb=(const float*)d_in[14];
  const float* dWih=(const float*)d_in[15], *dWhh=(const float*)d_in[16], *db=(const float*)d_in[17];
  const float* aw1 =(const float*)d_in[18], *aw2=(const float*)d_in[19];
  const float* aw3 =(const float*)d_in[20], *av =(const float*)d_in[21];
  const float* taw1=(const float*)d_in[22], *taw2=(const float*)d_in[23], *tavv=(const float*)d_in[24];
  const float* outW=(const float*)d_in[25], *outb=(const float*)d_in[26];
  float* ws  = (float*)d_ws;
  float* out = (float*)d_out;

  kInit<<<8, 256, 0, stream>>>(ws);
  kPrep<<<2*NN+TTAG+TLEN, 512, 0, stream>>>(src,tag,oid,emb_char,emb_tag,
                                            fWih,fb,bWih,bb,tWih,tb,dWih,db,ws);
  kEnc<<<3,512,0,stream>>>(fWhh,bWhh,tWhh,taw1,dWih,ws);
  kMid<<<NN,128,0,stream>>>(aw1,ws);
  kDec<<<GW,512,0,stream>>>(dWhh,dWih,aw2,aw3,av,taw2,tavv,ws);
  kLoss<<<256,256,0,stream>>>(outW,outb,oid,ws);
  kFinal<<<1,256,0,stream>>>(weight,ws,out);
}